// Round 1
// baseline (789.856 us; speedup 1.0000x reference)
//
#include <hip/hip_runtime.h>

#define T_ 8
#define N_ 10000
#define E_ 160000
#define G_ 32
#define C_ 10
#define F_ 128   // all hidden dims are 128

typedef _Float16 f16;
typedef _Float16 f16x2 __attribute__((ext_vector_type(2)));
typedef _Float16 f16x4 __attribute__((ext_vector_type(4)));
typedef _Float16 f16x8 __attribute__((ext_vector_type(8)));
typedef float floatx4 __attribute__((ext_vector_type(4)));

static constexpr size_t ROWS = (size_t)T_ * N_;   // 80000

// ---------------- workspace layout (bytes) ----------------
static constexpr size_t OFF_XH    = 0;                         // f16 [80000][128] (reused as H2)
static constexpr size_t OFF_A1    = 20480000;                  // f16 [80000][128] (reused as A2)
static constexpr size_t OFF_H1    = 40960000;                  // f16 [80000][128]
static constexpr size_t OFF_COL   = 61440000;                  // int [T][E]
static constexpr size_t OFF_COEF  = 66560000;                  // float [T][E]
static constexpr size_t OFF_DEG   = 71680000;                  // int [T][N]   -- zeroed
static constexpr size_t OFF_FILL  = 72000000;                  // int [T][N]   -- zeroed
static constexpr size_t OFF_CNTG  = 72320000;                  // int [T][G]   -- zeroed
static constexpr size_t OFF_H1S   = 72321024;                  // float [32][128] gru h, -- zeroed
static constexpr size_t OFF_H2S   = 72337408;                  // float [32][128] gru h, -- zeroed
static constexpr size_t ZERO_BYTES = 673792;                   // DEG..H2S contiguous
static constexpr size_t OFF_DINV  = 72353792;                  // float [T][N]
static constexpr size_t OFF_RP    = 72673792;                  // int [T][N+1]
static constexpr size_t OFF_WP    = 72994048;                  // f16 packed W1,W2 (2*16384)
static constexpr size_t OFF_PART  = 73059584;                  // float [T][64][32*128]
static constexpr size_t OFF_EMB   = 81448192;                  // float [T][32][128]
static constexpr size_t OFF_OUTS1 = 81579264;                  // float [T][32][128]
static constexpr size_t OFF_WT    = 81710336;                  // float 4x[128][384] transposed GRU W
// end ~82.5 MB

// ---------------- fp32 -> fp16 convert ----------------
__global__ void cvt_kernel(const float* __restrict__ x, f16* __restrict__ xh) {
  size_t i = ((size_t)blockIdx.x * 256 + threadIdx.x) * 4;
  float4 v = *(const float4*)(x + i);
  f16x4 o; o.x = (f16)v.x; o.y = (f16)v.y; o.z = (f16)v.z; o.w = (f16)v.w;
  *(f16x4*)(xh + i) = o;
}

// ---------------- degree histogram (by dst) ----------------
__global__ void deg_kernel(const int* __restrict__ ei, int* __restrict__ degI) {
  int gid = blockIdx.x * 256 + threadIdx.x;     // exactly T*E
  int t = gid / E_, e = gid - t * E_;
  int dst = ei[(size_t)t * 2 * E_ + E_ + e];
  atomicAdd(&degI[t * N_ + dst], 1);
}

// ---------------- pool group counts ----------------
__global__ void cnt_kernel(const int* __restrict__ batch, int* __restrict__ cntG) {
  int gid = blockIdx.x * 256 + threadIdx.x;
  if (gid < (int)ROWS) atomicAdd(&cntG[(gid / N_) * G_ + batch[gid]], 1);
}

// ---------------- dinv = rsqrt(deg+1) ----------------
__global__ void dinv_kernel(const int* __restrict__ degI, float* __restrict__ dinv) {
  int gid = blockIdx.x * 256 + threadIdx.x;
  if (gid < (int)ROWS) dinv[gid] = rsqrtf((float)degI[gid] + 1.0f);
}

// ---------------- per-t exclusive scan of deg -> row_ptr ----------------
__global__ void scan_kernel(const int* __restrict__ degI, int* __restrict__ rp) {
  __shared__ int lds[1024];
  __shared__ int carry;
  int t = blockIdx.x, tid = threadIdx.x;
  if (tid == 0) { carry = 0; rp[t * (N_ + 1)] = 0; }
  __syncthreads();
  const int* d = degI + t * N_;
  int* r = rp + t * (N_ + 1);
  for (int c0 = 0; c0 < N_; c0 += 1024) {
    int i = c0 + tid;
    int v = (i < N_) ? d[i] : 0;
    lds[tid] = v;
    __syncthreads();
    for (int ofs = 1; ofs < 1024; ofs <<= 1) {
      int add = (tid >= ofs) ? lds[tid - ofs] : 0;
      __syncthreads();
      lds[tid] += add;
      __syncthreads();
    }
    int inc = lds[tid] + carry;
    if (i < N_) r[i + 1] = inc;
    __syncthreads();
    if (tid == 1023) carry = inc;
    __syncthreads();
  }
}

// ---------------- CSR fill: col (src) + coef ----------------
__global__ void fill_kernel(const int* __restrict__ ei, const int* __restrict__ rp,
                            int* __restrict__ fillc, const float* __restrict__ dinv,
                            int* __restrict__ col, float* __restrict__ coef) {
  int gid = blockIdx.x * 256 + threadIdx.x;     // exactly T*E
  int t = gid / E_, e = gid - t * E_;
  int src = ei[(size_t)t * 2 * E_ + e];
  int dst = ei[(size_t)t * 2 * E_ + E_ + e];
  int pos = rp[t * (N_ + 1) + dst] + atomicAdd(&fillc[t * N_ + dst], 1);
  col[(size_t)t * E_ + pos]  = src;
  coef[(size_t)t * E_ + pos] = dinv[t * N_ + src] * dinv[t * N_ + dst];
}

// ---------------- aggregation: A = (D^-1/2 (Adj+I) D^-1/2) X  (one wave per row) ----------------
__global__ void agg_kernel(const f16* __restrict__ X, f16* __restrict__ A,
                           const int* __restrict__ rp, const int* __restrict__ col,
                           const float* __restrict__ coef, const float* __restrict__ dinv) {
  int wave = threadIdx.x >> 6, lane = threadIdx.x & 63;
  int row = blockIdx.x * 4 + wave;              // < 80000
  int t = row / N_, n = row - t * N_;
  float ds = dinv[row]; ds *= ds;               // self-loop coef
  f16x2 xv = *(const f16x2*)(X + (size_t)row * F_ + 2 * lane);
  float a0 = ds * (float)xv.x, a1 = ds * (float)xv.y;
  int beg = rp[t * (N_ + 1) + n], end = rp[t * (N_ + 1) + n + 1];
  const int*   cl = col  + (size_t)t * E_;
  const float* cf = coef + (size_t)t * E_;
  const f16*   Xt = X + (size_t)t * N_ * F_;
  for (int e = beg; e < end; ++e) {
    int s = cl[e]; float c = cf[e];
    f16x2 hv = *(const f16x2*)(Xt + (size_t)s * F_ + 2 * lane);
    a0 += c * (float)hv.x; a1 += c * (float)hv.y;
  }
  f16x2 o; o.x = (f16)a0; o.y = (f16)a1;
  *(f16x2*)(A + (size_t)row * F_ + 2 * lane) = o;
}

// ---------------- pack W into MFMA B-fragment layout (f16) ----------------
// Bfrag: lane holds B[k = kc*32 + (lane>>4)*8 + j][n = ct*16 + (lane&15)], j=0..7
__global__ void pack_kernel(const float* __restrict__ W1, const float* __restrict__ W2,
                            f16* __restrict__ Wp) {
  int idx = blockIdx.x * 256 + threadIdx.x;     // < 32768
  const float* W = (idx < 16384) ? W1 : W2;
  int l = idx & 16383;
  int j = l & 7, lane = (l >> 3) & 63, ct = (l >> 9) & 7, kc = (l >> 12) & 3;
  int k = kc * 32 + ((lane >> 4) & 3) * 8 + j;
  int n = ct * 16 + (lane & 15);
  Wp[idx] = (f16)W[k * 128 + n];
}

// ---------------- GEMM: O = relu(A @ W + b), A [80000][128] f16, MFMA 16x16x32 ----------------
__global__ __launch_bounds__(256) void gemm_kernel(const f16* __restrict__ A,
                                                   const f16* __restrict__ Wp,
                                                   const float* __restrict__ bias,
                                                   f16* __restrict__ O) {
  __shared__ f16x8 Bp[2048];                    // 32 KB packed W
  const f16x8* Wv = (const f16x8*)Wp;
  for (int i = threadIdx.x; i < 2048; i += 256) Bp[i] = Wv[i];
  __syncthreads();
  int wave = threadIdx.x >> 6, lane = threadIdx.x & 63;
  int quad = lane >> 4, m = lane & 15;
  int rowbase = blockIdx.x * 64 + wave * 16;
  const f16x8* Arow = (const f16x8*)(A + (size_t)(rowbase + m) * F_);
  floatx4 acc[8];
#pragma unroll
  for (int ct = 0; ct < 8; ++ct) { floatx4 z = {0.f, 0.f, 0.f, 0.f}; acc[ct] = z; }
#pragma unroll
  for (int kc = 0; kc < 4; ++kc) {
    f16x8 a = Arow[kc * 4 + quad];              // A[m=lane&15][k=kc*32+quad*8 ..+7]
#pragma unroll
    for (int ct = 0; ct < 8; ++ct)
      acc[ct] = __builtin_amdgcn_mfma_f32_16x16x32_f16(a, Bp[(kc * 8 + ct) * 64 + lane],
                                                       acc[ct], 0, 0, 0);
  }
  // D: col = lane&15, row = quad*4 + reg
#pragma unroll
  for (int ct = 0; ct < 8; ++ct) {
    int colc = ct * 16 + m;
    float bv = bias[colc];
#pragma unroll
    for (int r = 0; r < 4; ++r) {
      int row = rowbase + quad * 4 + r;
      float v = acc[ct][r] + bv;
      O[(size_t)row * F_ + colc] = (f16)fmaxf(v, 0.0f);
    }
  }
}

// ---------------- pool stage 1: per-(t, chunk) partial segment sums ----------------
__global__ void pool1_kernel(const f16* __restrict__ H, const int* __restrict__ batch,
                             float* __restrict__ partial) {
  __shared__ float acc[G_ * 128];
  for (int i = threadIdx.x; i < G_ * 128; i += 256) acc[i] = 0.0f;
  __syncthreads();
  int t = blockIdx.x, yb = blockIdx.y;
  int f = threadIdx.x & 127;
  int n1 = min(yb * 157 + 157, N_);
  for (int n = yb * 157 + (threadIdx.x >> 7); n < n1; n += 2) {
    int g = batch[t * N_ + n];
    atomicAdd(&acc[g * 128 + f], (float)H[((size_t)t * N_ + n) * F_ + f]);
  }
  __syncthreads();
  float* p = partial + ((size_t)t * 64 + yb) * (G_ * 128);
  for (int i = threadIdx.x; i < G_ * 128; i += 256) p[i] = acc[i];
}

// ---------------- pool stage 2 + mean ----------------
__global__ void pool2_kernel(const float* __restrict__ partial, const int* __restrict__ cntG,
                             float* __restrict__ emb) {
  int idx = blockIdx.x * 256 + threadIdx.x;     // < T*32*128
  int t = idx >> 12, gf = idx & 4095, g = gf >> 7;
  float s = 0.f;
  for (int b = 0; b < 64; ++b) s += partial[((size_t)t * 64 + b) * 4096 + gf];
  emb[idx] = s / fmaxf((float)cntG[t * G_ + g], 1.0f);
}

// ---------------- transpose GRU weights: WT[k*384+u] = W[u*128+k] ----------------
__global__ void wtr_kernel(const float* __restrict__ A0, const float* __restrict__ A1,
                           const float* __restrict__ A2, const float* __restrict__ A3,
                           float* __restrict__ WT) {
  int idx = blockIdx.x * 256 + threadIdx.x;     // < 4*49152
  int mm = idx / 49152, l = idx - mm * 49152;
  int u = l / 128, k = l - u * 128;
  const float* W = (mm == 0) ? A0 : (mm == 1) ? A1 : (mm == 2) ? A2 : A3;
  WT[(size_t)mm * 49152 + k * 384 + u] = W[u * 128 + k];
}

// ---------------- one GRU step (torch cell equations), fp32 ----------------
__global__ void gru_kernel(const float* __restrict__ xin, float* __restrict__ h,
                           float* __restrict__ outbuf,
                           const float* __restrict__ WTih, const float* __restrict__ WThh,
                           const float* __restrict__ bih, const float* __restrict__ bhh) {
  __shared__ float xs[2][128], hs[2][128];
  int gl = threadIdx.x >> 7, f = threadIdx.x & 127;
  int g = blockIdx.x * 2 + gl;
  xs[gl][f] = xin[g * 128 + f];
  hs[gl][f] = h[g * 128 + f];
  __syncthreads();
  float ir = bih[f], iz = bih[f + 128], inn = bih[f + 256];
  float hr = bhh[f], hz = bhh[f + 128], hn = bhh[f + 256];
  for (int k = 0; k < 128; ++k) {
    float xk = xs[gl][k], hk = hs[gl][k];
    const float* wi = WTih + k * 384;
    const float* wh = WThh + k * 384;
    ir  += xk * wi[f];
    iz  += xk * wi[128 + f];
    inn += xk * wi[256 + f];
    hr  += hk * wh[f];
    hz  += hk * wh[128 + f];
    hn  += hk * wh[256 + f];
  }
  float r = 1.f / (1.f + expf(-(ir + hr)));
  float z = 1.f / (1.f + expf(-(iz + hz)));
  float nn = tanhf(inn + r * hn);
  float hnew = (1.f - z) * nn + z * hs[gl][f];
  h[g * 128 + f] = hnew;
  if (outbuf) outbuf[g * 128 + f] = hnew;
}

// ---------------- final linear: out = h @ Wc^T + bc ----------------
__global__ void final_kernel(const float* __restrict__ h, const float* __restrict__ Wc,
                             const float* __restrict__ bc, float* __restrict__ out) {
  int tid = threadIdx.x;
  if (tid >= G_ * C_) return;
  int g = tid / C_, c = tid - g * C_;
  float s = bc[c];
  const float* hr = h + g * 128;
  const float* wr = Wc + c * 128;
  for (int k = 0; k < 128; ++k) s += hr[k] * wr[k];
  out[tid] = s;
}

extern "C" void kernel_launch(void* const* d_in, const int* in_sizes, int n_in,
                              void* d_out, int out_size, void* d_ws, size_t ws_size,
                              hipStream_t stream) {
  const float* x    = (const float*)d_in[0];
  const int*   ei   = (const int*)d_in[1];
  const int*   batch= (const int*)d_in[2];
  const float* W1   = (const float*)d_in[3];
  const float* b1   = (const float*)d_in[4];
  const float* W2   = (const float*)d_in[5];
  const float* b2   = (const float*)d_in[6];
  const float* Wih0 = (const float*)d_in[7];
  const float* Whh0 = (const float*)d_in[8];
  const float* bih0 = (const float*)d_in[9];
  const float* bhh0 = (const float*)d_in[10];
  const float* Wih1 = (const float*)d_in[11];
  const float* Whh1 = (const float*)d_in[12];
  const float* bih1 = (const float*)d_in[13];
  const float* bhh1 = (const float*)d_in[14];
  const float* Wc   = (const float*)d_in[15];
  const float* bc   = (const float*)d_in[16];
  float* out = (float*)d_out;

  char* ws = (char*)d_ws;
  f16*   Xh    = (f16*)(ws + OFF_XH);
  f16*   A1    = (f16*)(ws + OFF_A1);
  f16*   H1    = (f16*)(ws + OFF_H1);
  f16*   A2    = A1;                 // A1 dead after GEMM1
  f16*   H2    = Xh;                 // Xh dead after AGG1
  int*   col   = (int*)(ws + OFF_COL);
  float* coef  = (float*)(ws + OFF_COEF);
  int*   degI  = (int*)(ws + OFF_DEG);
  int*   fillc = (int*)(ws + OFF_FILL);
  int*   cntG  = (int*)(ws + OFF_CNTG);
  float* h1s   = (float*)(ws + OFF_H1S);
  float* h2s   = (float*)(ws + OFF_H2S);
  float* dinv  = (float*)(ws + OFF_DINV);
  int*   rp    = (int*)(ws + OFF_RP);
  f16*   Wp    = (f16*)(ws + OFF_WP);
  float* part  = (float*)(ws + OFF_PART);
  float* emb   = (float*)(ws + OFF_EMB);
  float* outs1 = (float*)(ws + OFF_OUTS1);
  float* WT    = (float*)(ws + OFF_WT);
  float* WTih0 = WT;
  float* WThh0 = WT + 49152;
  float* WTih1 = WT + 2 * 49152;
  float* WThh1 = WT + 3 * 49152;

  hipMemsetAsync(ws + OFF_DEG, 0, ZERO_BYTES, stream);

  cvt_kernel<<<10000, 256, 0, stream>>>(x, Xh);
  pack_kernel<<<128, 256, 0, stream>>>(W1, W2, Wp);
  wtr_kernel<<<768, 256, 0, stream>>>(Wih0, Whh0, Wih1, Whh1, WT);
  deg_kernel<<<5000, 256, 0, stream>>>(ei, degI);
  cnt_kernel<<<313, 256, 0, stream>>>(batch, cntG);
  dinv_kernel<<<313, 256, 0, stream>>>(degI, dinv);
  scan_kernel<<<8, 1024, 0, stream>>>(degI, rp);
  fill_kernel<<<5000, 256, 0, stream>>>(ei, rp, fillc, dinv, col, coef);

  agg_kernel<<<20000, 256, 0, stream>>>(Xh, A1, rp, col, coef, dinv);
  gemm_kernel<<<1250, 256, 0, stream>>>(A1, Wp, b1, H1);
  agg_kernel<<<20000, 256, 0, stream>>>(H1, A2, rp, col, coef, dinv);
  gemm_kernel<<<1250, 256, 0, stream>>>(A2, Wp + 16384, b2, H2);

  pool1_kernel<<<dim3(T_, 64), 256, 0, stream>>>(H2, batch, part);
  pool2_kernel<<<128, 256, 0, stream>>>(part, cntG, emb);

  for (int t = 0; t < T_; ++t)
    gru_kernel<<<16, 256, 0, stream>>>(emb + t * 4096, h1s, outs1 + t * 4096,
                                       WTih0, WThh0, bih0, bhh0);
  for (int t = 0; t < T_; ++t)
    gru_kernel<<<16, 256, 0, stream>>>(outs1 + t * 4096, h2s, (float*)nullptr,
                                       WTih1, WThh1, bih1, bhh1);

  final_kernel<<<1, 512, 0, stream>>>(h2s, Wc, bc, out);
}

// Round 2
// 666.504 us; speedup vs baseline: 1.1851x; 1.1851x over previous
//
#include <hip/hip_runtime.h>

#define T_ 8
#define N_ 10000
#define E_ 160000
#define G_ 32
#define C_ 10
#define F_ 128

typedef _Float16 f16;
typedef _Float16 f16x2 __attribute__((ext_vector_type(2)));
typedef _Float16 f16x4 __attribute__((ext_vector_type(4)));
typedef _Float16 f16x8 __attribute__((ext_vector_type(8)));
typedef float floatx4 __attribute__((ext_vector_type(4)));

static constexpr size_t ROWS = (size_t)T_ * N_;   // 80000

// ---------------- workspace layout (bytes) ----------------
static constexpr size_t OFF_XH    = 0;          // f16 [80000][128] (reused as H2)
static constexpr size_t OFF_A1    = 20480000;   // f16 [80000][128] (reused as A2)
static constexpr size_t OFF_H1    = 40960000;   // f16 [80000][128]
static constexpr size_t OFF_COL   = 61440000;   // int [T][E]
static constexpr size_t OFF_COEF  = 66560000;   // float [T][E]
static constexpr size_t OFF_DEG   = 71680000;   // int [T][N]    -- zeroed
static constexpr size_t OFF_FILL  = 72000000;   // int [T][N]    -- zeroed
static constexpr size_t OFF_CNTG  = 72320000;   // int [T][G]    -- zeroed
static constexpr size_t OFF_FILLB = 72321024;   // int [T][G]    -- zeroed
static constexpr size_t ZERO_BYTES = 642048;    // DEG..FILLB contiguous
static constexpr size_t OFF_DINV  = 72322048;   // float [T][N]
static constexpr size_t OFF_RP    = 72642048;   // int [T][N+1]
static constexpr size_t OFF_WP    = 72962080;   // f16 packed W1,W2 (2*16384), 16B-aligned
static constexpr size_t OFF_BRP   = 73027616;   // int [T*G+1]
static constexpr size_t OFF_BLIST = 73028648;   // int [80000]
static constexpr size_t OFF_EMB   = 73348656;   // float [T][32][128]
// end ~73.5 MB

// ---------------- fp32 -> fp16 convert ----------------
__global__ void cvt_kernel(const float* __restrict__ x, f16* __restrict__ xh) {
  size_t i = ((size_t)blockIdx.x * 256 + threadIdx.x) * 4;
  float4 v = *(const float4*)(x + i);
  f16x4 o; o.x = (f16)v.x; o.y = (f16)v.y; o.z = (f16)v.z; o.w = (f16)v.w;
  *(f16x4*)(xh + i) = o;
}

// ---------------- degree histogram (by dst) ----------------
__global__ void deg_kernel(const int* __restrict__ ei, int* __restrict__ degI) {
  int gid = blockIdx.x * 256 + threadIdx.x;     // exactly T*E
  int t = gid / E_, e = gid - t * E_;
  int dst = ei[(size_t)t * 2 * E_ + E_ + e];
  atomicAdd(&degI[t * N_ + dst], 1);
}

// ---------------- per-node: dinv + group counts ----------------
__global__ void node_kernel(const int* __restrict__ degI, float* __restrict__ dinv,
                            const int* __restrict__ batch, int* __restrict__ cntG) {
  int gid = blockIdx.x * 256 + threadIdx.x;
  if (gid < (int)ROWS) {
    dinv[gid] = rsqrtf((float)degI[gid] + 1.0f);
    atomicAdd(&cntG[(gid / N_) * G_ + batch[gid]], 1);
  }
}

// ---------------- per-t exclusive scan of deg -> row_ptr (shuffle-based) ----------------
__global__ void scan_kernel(const int* __restrict__ degI, int* __restrict__ rp) {
  __shared__ int wsum[16];
  __shared__ int carry;
  int t = blockIdx.x, tid = threadIdx.x, lane = tid & 63, wid = tid >> 6;
  if (tid == 0) { carry = 0; rp[t * (N_ + 1)] = 0; }
  __syncthreads();
  const int* d = degI + t * N_;
  int* r = rp + t * (N_ + 1);
  for (int c0 = 0; c0 < N_; c0 += 1024) {
    int i = c0 + tid;
    int v = (i < N_) ? d[i] : 0;
    for (int ofs = 1; ofs < 64; ofs <<= 1) {
      int u = __shfl_up(v, ofs);
      if (lane >= ofs) v += u;
    }
    if (lane == 63) wsum[wid] = v;
    __syncthreads();
    if (wid == 0) {
      int w = (lane < 16) ? wsum[lane] : 0;
      for (int ofs = 1; ofs < 16; ofs <<= 1) {
        int u = __shfl_up(w, ofs);
        if (lane >= ofs) w += u;
      }
      if (lane < 16) wsum[lane] = w;
    }
    __syncthreads();
    int base = carry + (wid ? wsum[wid - 1] : 0);
    if (i < N_) r[i + 1] = v + base;
    __syncthreads();
    if (tid == 0) carry += wsum[15];
    __syncthreads();
  }
}

// ---------------- tiny scan over [T*G] group counts -> brp ----------------
__global__ void bscan_kernel(const int* __restrict__ cntG, int* __restrict__ brp) {
  __shared__ int ws[4];
  int tid = threadIdx.x, lane = tid & 63, wid = tid >> 6;
  int v = cntG[tid];
  for (int ofs = 1; ofs < 64; ofs <<= 1) {
    int u = __shfl_up(v, ofs);
    if (lane >= ofs) v += u;
  }
  if (lane == 63) ws[wid] = v;
  __syncthreads();
  int base = 0;
  for (int w = 0; w < wid; ++w) base += ws[w];
  if (tid == 0) brp[0] = 0;
  brp[tid + 1] = v + base;
}

// ---------------- CSR fill: col (src) + coef ----------------
__global__ void fill_kernel(const int* __restrict__ ei, const int* __restrict__ rp,
                            int* __restrict__ fillc, const float* __restrict__ dinv,
                            int* __restrict__ col, float* __restrict__ coef) {
  int gid = blockIdx.x * 256 + threadIdx.x;     // exactly T*E
  int t = gid / E_, e = gid - t * E_;
  int src = ei[(size_t)t * 2 * E_ + e];
  int dst = ei[(size_t)t * 2 * E_ + E_ + e];
  int pos = rp[t * (N_ + 1) + dst] + atomicAdd(&fillc[t * N_ + dst], 1);
  col[(size_t)t * E_ + pos]  = src;
  coef[(size_t)t * E_ + pos] = dinv[t * N_ + src] * dinv[t * N_ + dst];
}

// ---------------- batch-CSR fill: node lists per (t,g) ----------------
__global__ void bfill_kernel(const int* __restrict__ batch, const int* __restrict__ brp,
                             int* __restrict__ fillb, int* __restrict__ blist) {
  int gid = blockIdx.x * 256 + threadIdx.x;
  if (gid < (int)ROWS) {
    int t = gid / N_;
    int g = batch[gid];
    int pos = brp[t * G_ + g] + atomicAdd(&fillb[t * G_ + g], 1);
    blist[pos] = gid;                           // global row id
  }
}

// ---------------- aggregation (XCD-swizzled, unroll-4) ----------------
// block b -> t = b%8 (== XCD id heuristic), keeps each snapshot's slice in one XCD's L2
__global__ void agg_kernel(const f16* __restrict__ X, f16* __restrict__ A,
                           const int* __restrict__ rp, const int* __restrict__ col,
                           const float* __restrict__ coef, const float* __restrict__ dinv) {
  int wave = threadIdx.x >> 6, lane = threadIdx.x & 63;
  int b = blockIdx.x;
  int t = b & 7, i = b >> 3;                    // 2500 i per t
  int n = i * 4 + wave;
  int row = t * N_ + n;
  float ds = dinv[row]; ds *= ds;               // self-loop coef
  f16x2 xv = *(const f16x2*)(X + (size_t)row * F_ + 2 * lane);
  float a00 = ds * (float)xv.x, a01 = ds * (float)xv.y;
  float a10 = 0.f, a11 = 0.f, a20 = 0.f, a21 = 0.f, a30 = 0.f, a31 = 0.f;
  int beg = rp[t * (N_ + 1) + n], end = rp[t * (N_ + 1) + n + 1];
  beg = __builtin_amdgcn_readfirstlane(beg);
  end = __builtin_amdgcn_readfirstlane(end);
  const int*   cl = col  + (size_t)t * E_;
  const float* cf = coef + (size_t)t * E_;
  const f16*   Xt = X + (size_t)t * N_ * F_;
  int e = beg;
  for (; e + 3 < end; e += 4) {
    int s0 = cl[e], s1 = cl[e + 1], s2 = cl[e + 2], s3 = cl[e + 3];
    float c0 = cf[e], c1 = cf[e + 1], c2 = cf[e + 2], c3 = cf[e + 3];
    f16x2 h0 = *(const f16x2*)(Xt + (size_t)s0 * F_ + 2 * lane);
    f16x2 h1 = *(const f16x2*)(Xt + (size_t)s1 * F_ + 2 * lane);
    f16x2 h2 = *(const f16x2*)(Xt + (size_t)s2 * F_ + 2 * lane);
    f16x2 h3 = *(const f16x2*)(Xt + (size_t)s3 * F_ + 2 * lane);
    a00 += c0 * (float)h0.x; a01 += c0 * (float)h0.y;
    a10 += c1 * (float)h1.x; a11 += c1 * (float)h1.y;
    a20 += c2 * (float)h2.x; a21 += c2 * (float)h2.y;
    a30 += c3 * (float)h3.x; a31 += c3 * (float)h3.y;
  }
  for (; e < end; ++e) {
    int s = cl[e]; float c = cf[e];
    f16x2 hv = *(const f16x2*)(Xt + (size_t)s * F_ + 2 * lane);
    a00 += c * (float)hv.x; a01 += c * (float)hv.y;
  }
  float r0 = (a00 + a10) + (a20 + a30);
  float r1 = (a01 + a11) + (a21 + a31);
  f16x2 o; o.x = (f16)r0; o.y = (f16)r1;
  *(f16x2*)(A + (size_t)row * F_ + 2 * lane) = o;
}

// ---------------- pack W into MFMA B-fragment layout (f16) ----------------
__global__ void pack_kernel(const float* __restrict__ W1, const float* __restrict__ W2,
                            f16* __restrict__ Wp) {
  int idx = blockIdx.x * 256 + threadIdx.x;     // < 32768
  const float* W = (idx < 16384) ? W1 : W2;
  int l = idx & 16383;
  int j = l & 7, lane = (l >> 3) & 63, ct = (l >> 9) & 7, kc = (l >> 12) & 3;
  int k = kc * 32 + ((lane >> 4) & 3) * 8 + j;
  int n = ct * 16 + (lane & 15);
  Wp[idx] = (f16)W[k * 128 + n];
}

// ---------------- GEMM: O = relu(A @ W + b), MFMA 16x16x32 ----------------
__global__ __launch_bounds__(256) void gemm_kernel(const f16* __restrict__ A,
                                                   const f16* __restrict__ Wp,
                                                   const float* __restrict__ bias,
                                                   f16* __restrict__ O) {
  __shared__ f16x8 Bp[2048];                    // 32 KB packed W
  const f16x8* Wv = (const f16x8*)Wp;
  for (int i = threadIdx.x; i < 2048; i += 256) Bp[i] = Wv[i];
  __syncthreads();
  int wave = threadIdx.x >> 6, lane = threadIdx.x & 63;
  int quad = lane >> 4, m = lane & 15;
  int rowbase = blockIdx.x * 64 + wave * 16;
  const f16x8* Arow = (const f16x8*)(A + (size_t)(rowbase + m) * F_);
  floatx4 acc[8];
#pragma unroll
  for (int ct = 0; ct < 8; ++ct) { floatx4 z = {0.f, 0.f, 0.f, 0.f}; acc[ct] = z; }
#pragma unroll
  for (int kc = 0; kc < 4; ++kc) {
    f16x8 a = Arow[kc * 4 + quad];
#pragma unroll
    for (int ct = 0; ct < 8; ++ct)
      acc[ct] = __builtin_amdgcn_mfma_f32_16x16x32_f16(a, Bp[(kc * 8 + ct) * 64 + lane],
                                                       acc[ct], 0, 0, 0);
  }
#pragma unroll
  for (int ct = 0; ct < 8; ++ct) {
    int colc = ct * 16 + m;
    float bv = bias[colc];
#pragma unroll
    for (int r = 0; r < 4; ++r) {
      int row = rowbase + quad * 4 + r;
      float v = acc[ct][r] + bv;
      O[(size_t)row * F_ + colc] = (f16)fmaxf(v, 0.0f);
    }
  }
}

// ---------------- pooling via batch-CSR gather (one wave per (t,g)) ----------------
__global__ void pool_kernel(const f16* __restrict__ H, const int* __restrict__ brp,
                            const int* __restrict__ blist, float* __restrict__ emb) {
  int wave = threadIdx.x >> 6, lane = threadIdx.x & 63;
  int idx = blockIdx.x * 4 + wave;              // t*G+g, < 256
  int beg = brp[idx], end = brp[idx + 1];
  beg = __builtin_amdgcn_readfirstlane(beg);
  end = __builtin_amdgcn_readfirstlane(end);
  float a00 = 0.f, a01 = 0.f, a10 = 0.f, a11 = 0.f;
  float a20 = 0.f, a21 = 0.f, a30 = 0.f, a31 = 0.f;
  int e = beg;
  for (; e + 3 < end; e += 4) {
    int r0 = blist[e], r1 = blist[e + 1], r2 = blist[e + 2], r3 = blist[e + 3];
    f16x2 v0 = *(const f16x2*)(H + (size_t)r0 * F_ + 2 * lane);
    f16x2 v1 = *(const f16x2*)(H + (size_t)r1 * F_ + 2 * lane);
    f16x2 v2 = *(const f16x2*)(H + (size_t)r2 * F_ + 2 * lane);
    f16x2 v3 = *(const f16x2*)(H + (size_t)r3 * F_ + 2 * lane);
    a00 += (float)v0.x; a01 += (float)v0.y;
    a10 += (float)v1.x; a11 += (float)v1.y;
    a20 += (float)v2.x; a21 += (float)v2.y;
    a30 += (float)v3.x; a31 += (float)v3.y;
  }
  for (; e < end; ++e) {
    int r = blist[e];
    f16x2 v = *(const f16x2*)(H + (size_t)r * F_ + 2 * lane);
    a00 += (float)v.x; a01 += (float)v.y;
  }
  float d = 1.0f / fmaxf((float)(end - beg), 1.0f);
  float2 o;
  o.x = ((a00 + a10) + (a20 + a30)) * d;
  o.y = ((a01 + a11) + (a21 + a31)) * d;
  *(float2*)(emb + (size_t)idx * F_ + 2 * lane) = o;
}

// ---------------- persistent GRU: 1 block per group, both layers, all T ----------------
__device__ __forceinline__ void gru_step(const float* __restrict__ xs, float* __restrict__ hs,
                                         const float* __restrict__ Wih, const float* __restrict__ Whh,
                                         const float* __restrict__ bih, const float* __restrict__ bhh,
                                         float* __restrict__ xout, int f, int kh,
                                         float (*par)[6]) {
  float s0 = 0.f, s1 = 0.f, s2 = 0.f, s3 = 0.f, s4 = 0.f, s5 = 0.f;
  int k0 = kh * 64;
  const float* wi0 = Wih + (size_t)f * 128;
  const float* wi1 = Wih + (size_t)(f + 128) * 128;
  const float* wi2 = Wih + (size_t)(f + 256) * 128;
  const float* wh0 = Whh + (size_t)f * 128;
  const float* wh1 = Whh + (size_t)(f + 128) * 128;
  const float* wh2 = Whh + (size_t)(f + 256) * 128;
  for (int k = k0; k < k0 + 64; k += 4) {
    float4 xv = *(const float4*)(xs + k);
    float4 hv = *(const float4*)(hs + k);
    float4 w;
    w = *(const float4*)(wi0 + k); s0 += xv.x * w.x + xv.y * w.y + xv.z * w.z + xv.w * w.w;
    w = *(const float4*)(wi1 + k); s1 += xv.x * w.x + xv.y * w.y + xv.z * w.z + xv.w * w.w;
    w = *(const float4*)(wi2 + k); s2 += xv.x * w.x + xv.y * w.y + xv.z * w.z + xv.w * w.w;
    w = *(const float4*)(wh0 + k); s3 += hv.x * w.x + hv.y * w.y + hv.z * w.z + hv.w * w.w;
    w = *(const float4*)(wh1 + k); s4 += hv.x * w.x + hv.y * w.y + hv.z * w.z + hv.w * w.w;
    w = *(const float4*)(wh2 + k); s5 += hv.x * w.x + hv.y * w.y + hv.z * w.z + hv.w * w.w;
  }
  int tid = kh * 128 + f;
  par[tid][0] = s0; par[tid][1] = s1; par[tid][2] = s2;
  par[tid][3] = s3; par[tid][4] = s4; par[tid][5] = s5;
  __syncthreads();
  if (kh == 0) {
    float ir  = bih[f]       + par[f][0] + par[f + 128][0];
    float iz  = bih[f + 128] + par[f][1] + par[f + 128][1];
    float inn = bih[f + 256] + par[f][2] + par[f + 128][2];
    float hr  = bhh[f]       + par[f][3] + par[f + 128][3];
    float hz  = bhh[f + 128] + par[f][4] + par[f + 128][4];
    float hn  = bhh[f + 256] + par[f][5] + par[f + 128][5];
    float r = 1.f / (1.f + expf(-(ir + hr)));
    float z = 1.f / (1.f + expf(-(iz + hz)));
    float nn = tanhf(inn + r * hn);
    float hnew = (1.f - z) * nn + z * hs[f];
    hs[f] = hnew;
    if (xout) xout[f] = hnew;
  }
  __syncthreads();
}

__global__ __launch_bounds__(256) void gru_all_kernel(
    const float* __restrict__ emb,
    const float* __restrict__ Wih0, const float* __restrict__ Whh0,
    const float* __restrict__ bih0, const float* __restrict__ bhh0,
    const float* __restrict__ Wih1, const float* __restrict__ Whh1,
    const float* __restrict__ bih1, const float* __restrict__ bhh1,
    const float* __restrict__ Wc, const float* __restrict__ bc,
    float* __restrict__ out) {
  __shared__ __align__(16) float h1[128];
  __shared__ __align__(16) float h2[128];
  __shared__ __align__(16) float xs[128];
  __shared__ __align__(16) float x2[128];
  __shared__ float par[256][6];
  int g = blockIdx.x;
  int f = threadIdx.x & 127, kh = threadIdx.x >> 7;
  if (kh == 0) { h1[f] = 0.f; h2[f] = 0.f; }
  __syncthreads();
  for (int t = 0; t < T_; ++t) {
    if (kh == 0) xs[f] = emb[((size_t)t * G_ + g) * 128 + f];
    __syncthreads();
    gru_step(xs, h1, Wih0, Whh0, bih0, bhh0, x2, f, kh, par);
    gru_step(x2, h2, Wih1, Whh1, bih1, bhh1, (float*)nullptr, f, kh, par);
  }
  if (threadIdx.x < C_) {
    int c = threadIdx.x;
    float s = bc[c];
    const float* wr = Wc + (size_t)c * 128;
    for (int k = 0; k < 128; k += 4) {
      float4 w = *(const float4*)(wr + k);
      float4 h = *(const float4*)(h2 + k);
      s += h.x * w.x + h.y * w.y + h.z * w.z + h.w * w.w;
    }
    out[g * C_ + c] = s;
  }
}

extern "C" void kernel_launch(void* const* d_in, const int* in_sizes, int n_in,
                              void* d_out, int out_size, void* d_ws, size_t ws_size,
                              hipStream_t stream) {
  const float* x    = (const float*)d_in[0];
  const int*   ei   = (const int*)d_in[1];
  const int*   batch= (const int*)d_in[2];
  const float* W1   = (const float*)d_in[3];
  const float* b1   = (const float*)d_in[4];
  const float* W2   = (const float*)d_in[5];
  const float* b2   = (const float*)d_in[6];
  const float* Wih0 = (const float*)d_in[7];
  const float* Whh0 = (const float*)d_in[8];
  const float* bih0 = (const float*)d_in[9];
  const float* bhh0 = (const float*)d_in[10];
  const float* Wih1 = (const float*)d_in[11];
  const float* Whh1 = (const float*)d_in[12];
  const float* bih1 = (const float*)d_in[13];
  const float* bhh1 = (const float*)d_in[14];
  const float* Wc   = (const float*)d_in[15];
  const float* bc   = (const float*)d_in[16];
  float* out = (float*)d_out;

  char* ws = (char*)d_ws;
  f16*   Xh    = (f16*)(ws + OFF_XH);
  f16*   A1    = (f16*)(ws + OFF_A1);
  f16*   H1    = (f16*)(ws + OFF_H1);
  f16*   A2    = A1;                 // A1 dead after GEMM1
  f16*   H2    = Xh;                 // Xh dead after AGG1
  int*   col   = (int*)(ws + OFF_COL);
  float* coef  = (float*)(ws + OFF_COEF);
  int*   degI  = (int*)(ws + OFF_DEG);
  int*   fillc = (int*)(ws + OFF_FILL);
  int*   cntG  = (int*)(ws + OFF_CNTG);
  int*   fillb = (int*)(ws + OFF_FILLB);
  float* dinv  = (float*)(ws + OFF_DINV);
  int*   rp    = (int*)(ws + OFF_RP);
  f16*   Wp    = (f16*)(ws + OFF_WP);
  int*   brp   = (int*)(ws + OFF_BRP);
  int*   blist = (int*)(ws + OFF_BLIST);
  float* emb   = (float*)(ws + OFF_EMB);

  hipMemsetAsync(ws + OFF_DEG, 0, ZERO_BYTES, stream);

  cvt_kernel<<<10000, 256, 0, stream>>>(x, Xh);
  pack_kernel<<<128, 256, 0, stream>>>(W1, W2, Wp);
  deg_kernel<<<5000, 256, 0, stream>>>(ei, degI);
  node_kernel<<<313, 256, 0, stream>>>(degI, dinv, batch, cntG);
  scan_kernel<<<8, 1024, 0, stream>>>(degI, rp);
  bscan_kernel<<<1, 256, 0, stream>>>(cntG, brp);
  fill_kernel<<<5000, 256, 0, stream>>>(ei, rp, fillc, dinv, col, coef);
  bfill_kernel<<<313, 256, 0, stream>>>(batch, brp, fillb, blist);

  agg_kernel<<<20000, 256, 0, stream>>>(Xh, A1, rp, col, coef, dinv);
  gemm_kernel<<<1250, 256, 0, stream>>>(A1, Wp, b1, H1);
  agg_kernel<<<20000, 256, 0, stream>>>(H1, A2, rp, col, coef, dinv);
  gemm_kernel<<<1250, 256, 0, stream>>>(A2, Wp + 16384, b2, H2);

  pool_kernel<<<64, 256, 0, stream>>>(H2, brp, blist, emb);

  gru_all_kernel<<<32, 256, 0, stream>>>(emb, Wih0, Whh0, bih0, bhh0,
                                         Wih1, Whh1, bih1, bhh1, Wc, bc, out);
}

// Round 4
// 583.613 us; speedup vs baseline: 1.3534x; 1.1420x over previous
//
#include <hip/hip_runtime.h>

#define T_ 8
#define N_ 10000
#define E_ 160000
#define G_ 32
#define C_ 10
#define F_ 128

typedef _Float16 f16;
typedef _Float16 f16x2 __attribute__((ext_vector_type(2)));
typedef _Float16 f16x4 __attribute__((ext_vector_type(4)));
typedef _Float16 f16x8 __attribute__((ext_vector_type(8)));
typedef float floatx4 __attribute__((ext_vector_type(4)));

static constexpr size_t ROWS = (size_t)T_ * N_;   // 80000

// ---------------- workspace layout (bytes) ----------------
static constexpr size_t OFF_XH    = 0;          // f16 [80000][128] (reused as H2)
static constexpr size_t OFF_A1    = 20480000;   // f16 [80000][128] (reused as A2)
static constexpr size_t OFF_H1    = 40960000;   // f16 [80000][128]
static constexpr size_t OFF_COL   = 61440000;   // int [T][E]
static constexpr size_t OFF_COEF  = 66560000;   // float [T][E]
static constexpr size_t OFF_DEG   = 71680000;   // int [T][N]    -- zeroed
static constexpr size_t OFF_FILL  = 72000000;   // int [T][N]    -- zeroed
static constexpr size_t OFF_CNTG  = 72320000;   // int [T][G]    -- zeroed
static constexpr size_t OFF_FILLB = 72321024;   // int [T][G]    -- zeroed
static constexpr size_t ZERO_BYTES = 642048;    // DEG..FILLB contiguous
static constexpr size_t OFF_DINV  = 72322048;   // float [T][N]
static constexpr size_t OFF_RP    = 72642048;   // int [T][N+1]
static constexpr size_t OFF_WP    = 72962080;   // f16 packed W1,W2 (2*16384)
static constexpr size_t OFF_BRP   = 73027616;   // int [T*G+1]
static constexpr size_t OFF_BLIST = 73028648;   // int [80000]
static constexpr size_t OFF_EMBH  = 73348656;   // f16 [256][128]
static constexpr size_t OFF_GPACK = 73414192;   // f16 4*49152 packed GRU weights
static constexpr size_t OFF_GI0   = 73807408;   // float [256][384]
static constexpr size_t OFF_GI1   = 74200624;   // float [256][384]
static constexpr size_t OFF_X2H   = 74593840;   // f16 [256][128]
// end ~74.7 MB

// ---------------- fp32 -> fp16 convert ----------------
__global__ void cvt_kernel(const float* __restrict__ x, f16* __restrict__ xh) {
  size_t i = ((size_t)blockIdx.x * 256 + threadIdx.x) * 4;
  float4 v = *(const float4*)(x + i);
  f16x4 o; o.x = (f16)v.x; o.y = (f16)v.y; o.z = (f16)v.z; o.w = (f16)v.w;
  *(f16x4*)(xh + i) = o;
}

// ---------------- degree histogram (by dst) ----------------
__global__ void deg_kernel(const int* __restrict__ ei, int* __restrict__ degI) {
  int gid = blockIdx.x * 256 + threadIdx.x;     // exactly T*E
  int t = gid / E_, e = gid - t * E_;
  int dst = ei[(size_t)t * 2 * E_ + E_ + e];
  atomicAdd(&degI[t * N_ + dst], 1);
}

// ---------------- per-node: dinv + group counts ----------------
__global__ void node_kernel(const int* __restrict__ degI, float* __restrict__ dinv,
                            const int* __restrict__ batch, int* __restrict__ cntG) {
  int gid = blockIdx.x * 256 + threadIdx.x;
  if (gid < (int)ROWS) {
    dinv[gid] = rsqrtf((float)degI[gid] + 1.0f);
    atomicAdd(&cntG[(gid / N_) * G_ + batch[gid]], 1);
  }
}

// ---------------- per-t exclusive scan of deg -> row_ptr ----------------
__global__ void scan_kernel(const int* __restrict__ degI, int* __restrict__ rp) {
  __shared__ int wsum[16];
  __shared__ int carry;
  int t = blockIdx.x, tid = threadIdx.x, lane = tid & 63, wid = tid >> 6;
  if (tid == 0) { carry = 0; rp[t * (N_ + 1)] = 0; }
  __syncthreads();
  const int* d = degI + t * N_;
  int* r = rp + t * (N_ + 1);
  for (int c0 = 0; c0 < N_; c0 += 1024) {
    int i = c0 + tid;
    int v = (i < N_) ? d[i] : 0;
    for (int ofs = 1; ofs < 64; ofs <<= 1) {
      int u = __shfl_up(v, ofs);
      if (lane >= ofs) v += u;
    }
    if (lane == 63) wsum[wid] = v;
    __syncthreads();
    if (wid == 0) {
      int w = (lane < 16) ? wsum[lane] : 0;
      for (int ofs = 1; ofs < 16; ofs <<= 1) {
        int u = __shfl_up(w, ofs);
        if (lane >= ofs) w += u;
      }
      if (lane < 16) wsum[lane] = w;
    }
    __syncthreads();
    int base = carry + (wid ? wsum[wid - 1] : 0);
    if (i < N_) r[i + 1] = v + base;
    __syncthreads();
    if (tid == 0) carry += wsum[15];
    __syncthreads();
  }
}

// ---------------- tiny scan over [T*G] group counts -> brp ----------------
__global__ void bscan_kernel(const int* __restrict__ cntG, int* __restrict__ brp) {
  __shared__ int ws[4];
  int tid = threadIdx.x, lane = tid & 63, wid = tid >> 6;
  int v = cntG[tid];
  for (int ofs = 1; ofs < 64; ofs <<= 1) {
    int u = __shfl_up(v, ofs);
    if (lane >= ofs) v += u;
  }
  if (lane == 63) ws[wid] = v;
  __syncthreads();
  int base = 0;
  for (int w = 0; w < wid; ++w) base += ws[w];
  if (tid == 0) brp[0] = 0;
  brp[tid + 1] = v + base;
}

// ---------------- CSR fill: col (src) + coef ----------------
__global__ void fill_kernel(const int* __restrict__ ei, const int* __restrict__ rp,
                            int* __restrict__ fillc, const float* __restrict__ dinv,
                            int* __restrict__ col, float* __restrict__ coef) {
  int gid = blockIdx.x * 256 + threadIdx.x;     // exactly T*E
  int t = gid / E_, e = gid - t * E_;
  int src = ei[(size_t)t * 2 * E_ + e];
  int dst = ei[(size_t)t * 2 * E_ + E_ + e];
  int pos = rp[t * (N_ + 1) + dst] + atomicAdd(&fillc[t * N_ + dst], 1);
  col[(size_t)t * E_ + pos]  = src;
  coef[(size_t)t * E_ + pos] = dinv[t * N_ + src] * dinv[t * N_ + dst];
}

// ---------------- batch-CSR fill: node lists per (t,g) ----------------
__global__ void bfill_kernel(const int* __restrict__ batch, const int* __restrict__ brp,
                             int* __restrict__ fillb, int* __restrict__ blist) {
  int gid = blockIdx.x * 256 + threadIdx.x;
  if (gid < (int)ROWS) {
    int t = gid / N_;
    int g = batch[gid];
    int pos = brp[t * G_ + g] + atomicAdd(&fillb[t * G_ + g], 1);
    blist[pos] = gid;                           // global row id
  }
}

// ---------------- aggregation (XCD-swizzled, unroll-4) ----------------
__global__ void agg_kernel(const f16* __restrict__ X, f16* __restrict__ A,
                           const int* __restrict__ rp, const int* __restrict__ col,
                           const float* __restrict__ coef, const float* __restrict__ dinv) {
  int wave = threadIdx.x >> 6, lane = threadIdx.x & 63;
  int b = blockIdx.x;
  int t = b & 7, i = b >> 3;
  int n = i * 4 + wave;
  int row = t * N_ + n;
  float ds = dinv[row]; ds *= ds;
  f16x2 xv = *(const f16x2*)(X + (size_t)row * F_ + 2 * lane);
  float a00 = ds * (float)xv.x, a01 = ds * (float)xv.y;
  float a10 = 0.f, a11 = 0.f, a20 = 0.f, a21 = 0.f, a30 = 0.f, a31 = 0.f;
  int beg = rp[t * (N_ + 1) + n], end = rp[t * (N_ + 1) + n + 1];
  beg = __builtin_amdgcn_readfirstlane(beg);
  end = __builtin_amdgcn_readfirstlane(end);
  const int*   cl = col  + (size_t)t * E_;
  const float* cf = coef + (size_t)t * E_;
  const f16*   Xt = X + (size_t)t * N_ * F_;
  int e = beg;
  for (; e + 3 < end; e += 4) {
    int s0 = cl[e], s1 = cl[e + 1], s2 = cl[e + 2], s3 = cl[e + 3];
    float c0 = cf[e], c1 = cf[e + 1], c2 = cf[e + 2], c3 = cf[e + 3];
    f16x2 h0 = *(const f16x2*)(Xt + (size_t)s0 * F_ + 2 * lane);
    f16x2 h1 = *(const f16x2*)(Xt + (size_t)s1 * F_ + 2 * lane);
    f16x2 h2 = *(const f16x2*)(Xt + (size_t)s2 * F_ + 2 * lane);
    f16x2 h3 = *(const f16x2*)(Xt + (size_t)s3 * F_ + 2 * lane);
    a00 += c0 * (float)h0.x; a01 += c0 * (float)h0.y;
    a10 += c1 * (float)h1.x; a11 += c1 * (float)h1.y;
    a20 += c2 * (float)h2.x; a21 += c2 * (float)h2.y;
    a30 += c3 * (float)h3.x; a31 += c3 * (float)h3.y;
  }
  for (; e < end; ++e) {
    int s = cl[e]; float c = cf[e];
    f16x2 hv = *(const f16x2*)(Xt + (size_t)s * F_ + 2 * lane);
    a00 += c * (float)hv.x; a01 += c * (float)hv.y;
  }
  float r0 = (a00 + a10) + (a20 + a30);
  float r1 = (a01 + a11) + (a21 + a31);
  f16x2 o; o.x = (f16)r0; o.y = (f16)r1;
  *(f16x2*)(A + (size_t)row * F_ + 2 * lane) = o;
}

// ---------------- pack W1/W2 into MFMA B-fragment layout (f16) ----------------
__global__ void pack_kernel(const float* __restrict__ W1, const float* __restrict__ W2,
                            f16* __restrict__ Wp) {
  int idx = blockIdx.x * 256 + threadIdx.x;     // < 32768
  const float* W = (idx < 16384) ? W1 : W2;
  int l = idx & 16383;
  int j = l & 7, lane = (l >> 3) & 63, ct = (l >> 9) & 7, kc = (l >> 12) & 3;
  int k = kc * 32 + ((lane >> 4) & 3) * 8 + j;
  int n = ct * 16 + (lane & 15);
  Wp[idx] = (f16)W[k * 128 + n];
}

// ---------------- pack GRU weights [384][128] -> B-frag layout, B[k][u]=W[u][k] ----------------
// storage: (((mat*24 + nt)*4 + kc)*64 + lane)*8 + j ; k=kc*32+(lane>>4)*8+j ; u=nt*16+(lane&15)
__global__ void gpack_kernel(const float* __restrict__ A0, const float* __restrict__ A1,
                             const float* __restrict__ A2, const float* __restrict__ A3,
                             f16* __restrict__ gp) {
  int idx = blockIdx.x * 256 + threadIdx.x;     // < 196608
  int mat = idx / 49152, l = idx - mat * 49152;
  int j = l & 7, lane = (l >> 3) & 63, kc = (l >> 9) & 3, nt = l >> 11;
  int k = kc * 32 + ((lane >> 4) & 3) * 8 + j;
  int u = nt * 16 + (lane & 15);
  const float* W = (mat == 0) ? A0 : (mat == 1) ? A1 : (mat == 2) ? A2 : A3;
  gp[idx] = (f16)W[u * 128 + k];
}

// ---------------- GEMM: O = relu(A @ W + b), MFMA 16x16x32 ----------------
__global__ __launch_bounds__(256) void gemm_kernel(const f16* __restrict__ A,
                                                   const f16* __restrict__ Wp,
                                                   const float* __restrict__ bias,
                                                   f16* __restrict__ O) {
  __shared__ f16x8 Bp[2048];                    // 32 KB packed W
  const f16x8* Wv = (const f16x8*)Wp;
  for (int i = threadIdx.x; i < 2048; i += 256) Bp[i] = Wv[i];
  __syncthreads();
  int wave = threadIdx.x >> 6, lane = threadIdx.x & 63;
  int quad = lane >> 4, m = lane & 15;
  int rowbase = blockIdx.x * 64 + wave * 16;
  const f16x8* Arow = (const f16x8*)(A + (size_t)(rowbase + m) * F_);
  floatx4 acc[8];
#pragma unroll
  for (int ct = 0; ct < 8; ++ct) { floatx4 z = {0.f, 0.f, 0.f, 0.f}; acc[ct] = z; }
#pragma unroll
  for (int kc = 0; kc < 4; ++kc) {
    f16x8 a = Arow[kc * 4 + quad];
#pragma unroll
    for (int ct = 0; ct < 8; ++ct)
      acc[ct] = __builtin_amdgcn_mfma_f32_16x16x32_f16(a, Bp[(kc * 8 + ct) * 64 + lane],
                                                       acc[ct], 0, 0, 0);
  }
#pragma unroll
  for (int ct = 0; ct < 8; ++ct) {
    int colc = ct * 16 + m;
    float bv = bias[colc];
#pragma unroll
    for (int r = 0; r < 4; ++r) {
      int row = rowbase + quad * 4 + r;
      float v = acc[ct][r] + bv;
      O[(size_t)row * F_ + colc] = (f16)fmaxf(v, 0.0f);
    }
  }
}

// ---------------- pooling via batch-CSR gather -> f16 emb ----------------
__global__ void pool_kernel(const f16* __restrict__ H, const int* __restrict__ brp,
                            const int* __restrict__ blist, f16* __restrict__ embh) {
  int wave = threadIdx.x >> 6, lane = threadIdx.x & 63;
  int idx = blockIdx.x * 4 + wave;              // t*G+g, < 256
  int beg = brp[idx], end = brp[idx + 1];
  beg = __builtin_amdgcn_readfirstlane(beg);
  end = __builtin_amdgcn_readfirstlane(end);
  float a00 = 0.f, a01 = 0.f, a10 = 0.f, a11 = 0.f;
  float a20 = 0.f, a21 = 0.f, a30 = 0.f, a31 = 0.f;
  int e = beg;
  for (; e + 3 < end; e += 4) {
    int r0 = blist[e], r1 = blist[e + 1], r2 = blist[e + 2], r3 = blist[e + 3];
    f16x2 v0 = *(const f16x2*)(H + (size_t)r0 * F_ + 2 * lane);
    f16x2 v1 = *(const f16x2*)(H + (size_t)r1 * F_ + 2 * lane);
    f16x2 v2 = *(const f16x2*)(H + (size_t)r2 * F_ + 2 * lane);
    f16x2 v3 = *(const f16x2*)(H + (size_t)r3 * F_ + 2 * lane);
    a00 += (float)v0.x; a01 += (float)v0.y;
    a10 += (float)v1.x; a11 += (float)v1.y;
    a20 += (float)v2.x; a21 += (float)v2.y;
    a30 += (float)v3.x; a31 += (float)v3.y;
  }
  for (; e < end; ++e) {
    int r = blist[e];
    f16x2 v = *(const f16x2*)(H + (size_t)r * F_ + 2 * lane);
    a00 += (float)v.x; a01 += (float)v.y;
  }
  float d = 1.0f / fmaxf((float)(end - beg), 1.0f);
  f16x2 o;
  o.x = (f16)(((a00 + a10) + (a20 + a30)) * d);
  o.y = (f16)(((a01 + a11) + (a21 + a31)) * d);
  *(f16x2*)(embh + (size_t)idx * F_ + 2 * lane) = o;
}

// ---------------- gi0 = emb @ Wih0^T : M=256, K=128, N=384 ----------------
__global__ __launch_bounds__(256) void gi0_kernel(const f16* __restrict__ embh,
                                                  const f16* __restrict__ gp,
                                                  float* __restrict__ gi0) {
  int wave = threadIdx.x >> 6, lane = threadIdx.x & 63;
  int quad = lane >> 4, mm = lane & 15;
  int rowbase = blockIdx.x * 64 + wave * 16;    // grid 4
  const f16* Arow = embh + (size_t)(rowbase + mm) * 128;
  floatx4 acc[24];
#pragma unroll
  for (int nt = 0; nt < 24; ++nt) { floatx4 z = {0.f, 0.f, 0.f, 0.f}; acc[nt] = z; }
#pragma unroll
  for (int kc = 0; kc < 4; ++kc) {
    f16x8 a = *(const f16x8*)(Arow + kc * 32 + quad * 8);
#pragma unroll
    for (int nt = 0; nt < 24; ++nt) {
      f16x8 b = *(const f16x8*)(gp + (size_t)(((nt * 4 + kc) * 64 + lane)) * 8);
      acc[nt] = __builtin_amdgcn_mfma_f32_16x16x32_f16(a, b, acc[nt], 0, 0, 0);
    }
  }
#pragma unroll
  for (int nt = 0; nt < 24; ++nt)
#pragma unroll
    for (int r = 0; r < 4; ++r)
      gi0[(size_t)(rowbase + quad * 4 + r) * 384 + nt * 16 + mm] = acc[nt][r];
}

// ---------------- persistent GRU: 1 block, B-frags in VGPRs, 3 phases ----------------
#define GH_ST 400

__device__ __forceinline__ void load_bfrags(const f16* __restrict__ gpm, int wave, int lane,
                                            f16x8* B) {
#pragma unroll
  for (int i = 0; i < 6; ++i)
#pragma unroll
    for (int kc = 0; kc < 4; ++kc)
      B[i * 4 + kc] = *(const f16x8*)(gpm + (size_t)((((wave * 6 + i) * 4 + kc) * 64 + lane)) * 8);
}

__device__ __forceinline__ void recurrence_phase(
    const f16* __restrict__ gpm,        // packed Whh for this layer
    const float* __restrict__ gisrc,    // [256][384]
    const float* __restrict__ bih, const float* __restrict__ bhh,
    f16* __restrict__ x2h,              // nullptr for layer 1
    float* __restrict__ h,              // [16] per-thread fp32 state
    float* __restrict__ ghbuf, f16* __restrict__ hbuf) {
  int tid = threadIdx.x, wave = tid >> 6, lane = tid & 63;
  int quad = lane >> 4, mm = lane & 15;
  int hm = tid >> 3, hf = (tid & 7) * 16;
  f16x8 B[24];
  load_bfrags(gpm, wave, lane, B);
  // biases (combined where possible)
  float br[16], bz[16], bni[16], bnh[16];
#pragma unroll
  for (int q = 0; q < 4; ++q) {
    float4 a = *(const float4*)(bih + hf + q * 4);
    float4 b = *(const float4*)(bhh + hf + q * 4);
    float4 c = *(const float4*)(bih + 128 + hf + q * 4);
    float4 d = *(const float4*)(bhh + 128 + hf + q * 4);
    float4 e = *(const float4*)(bih + 256 + hf + q * 4);
    float4 f = *(const float4*)(bhh + 256 + hf + q * 4);
    br[q*4+0]=a.x+b.x; br[q*4+1]=a.y+b.y; br[q*4+2]=a.z+b.z; br[q*4+3]=a.w+b.w;
    bz[q*4+0]=c.x+d.x; bz[q*4+1]=c.y+d.y; bz[q*4+2]=c.z+d.z; bz[q*4+3]=c.w+d.w;
    bni[q*4+0]=e.x; bni[q*4+1]=e.y; bni[q*4+2]=e.z; bni[q*4+3]=e.w;
    bnh[q*4+0]=f.x; bnh[q*4+1]=f.y; bnh[q*4+2]=f.z; bnh[q*4+3]=f.w;
  }
  // init h = 0, hbuf = 0
#pragma unroll
  for (int k = 0; k < 16; ++k) h[k] = 0.f;
#pragma unroll
  for (int k = 0; k < 16; k += 2) {
    f16x2 z2; z2.x = (f16)0.f; z2.y = (f16)0.f;
    *(f16x2*)(hbuf + hm * 136 + hf + k) = z2;
  }
  __syncthreads();
  for (int t = 0; t < T_; ++t) {
    // gh = h @ Whh^T for this wave's 96 columns
    floatx4 acc[12];
#pragma unroll
    for (int i = 0; i < 12; ++i) { floatx4 z = {0.f, 0.f, 0.f, 0.f}; acc[i] = z; }
#pragma unroll
    for (int kc = 0; kc < 4; ++kc) {
      f16x8 a0 = *(const f16x8*)(hbuf + mm * 136 + kc * 32 + quad * 8);
      f16x8 a1 = *(const f16x8*)(hbuf + (16 + mm) * 136 + kc * 32 + quad * 8);
#pragma unroll
      for (int i = 0; i < 6; ++i) {
        acc[i]     = __builtin_amdgcn_mfma_f32_16x16x32_f16(a0, B[i * 4 + kc], acc[i], 0, 0, 0);
        acc[6 + i] = __builtin_amdgcn_mfma_f32_16x16x32_f16(a1, B[i * 4 + kc], acc[6 + i], 0, 0, 0);
      }
    }
#pragma unroll
    for (int i = 0; i < 6; ++i)
#pragma unroll
      for (int r = 0; r < 4; ++r) {
        ghbuf[(quad * 4 + r) * GH_ST + wave * 96 + i * 16 + mm]      = acc[i][r];
        ghbuf[(16 + quad * 4 + r) * GH_ST + wave * 96 + i * 16 + mm] = acc[6 + i][r];
      }
    __syncthreads();
    // elementwise GRU update: thread owns (hm, hf..hf+15)
    const float* gi = gisrc + (size_t)(t * 32 + hm) * 384;
    float gr[16], gz[16], gn[16], hr[16], hz[16], hn[16];
#pragma unroll
    for (int q = 0; q < 4; ++q) {
      float4 a = *(const float4*)(gi + hf + q * 4);
      float4 b = *(const float4*)(gi + 128 + hf + q * 4);
      float4 c = *(const float4*)(gi + 256 + hf + q * 4);
      gr[q*4+0]=a.x; gr[q*4+1]=a.y; gr[q*4+2]=a.z; gr[q*4+3]=a.w;
      gz[q*4+0]=b.x; gz[q*4+1]=b.y; gz[q*4+2]=b.z; gz[q*4+3]=b.w;
      gn[q*4+0]=c.x; gn[q*4+1]=c.y; gn[q*4+2]=c.z; gn[q*4+3]=c.w;
      float4 d = *(const float4*)(ghbuf + hm * GH_ST + hf + q * 4);
      float4 e = *(const float4*)(ghbuf + hm * GH_ST + 128 + hf + q * 4);
      float4 f = *(const float4*)(ghbuf + hm * GH_ST + 256 + hf + q * 4);
      hr[q*4+0]=d.x; hr[q*4+1]=d.y; hr[q*4+2]=d.z; hr[q*4+3]=d.w;
      hz[q*4+0]=e.x; hz[q*4+1]=e.y; hz[q*4+2]=e.z; hz[q*4+3]=e.w;
      hn[q*4+0]=f.x; hn[q*4+1]=f.y; hn[q*4+2]=f.z; hn[q*4+3]=f.w;
    }
#pragma unroll
    for (int k = 0; k < 16; ++k) {
      float r = 1.f / (1.f + expf(-(gr[k] + hr[k] + br[k])));
      float z = 1.f / (1.f + expf(-(gz[k] + hz[k] + bz[k])));
      float nn = tanhf(gn[k] + bni[k] + r * (hn[k] + bnh[k]));
      h[k] = (1.f - z) * nn + z * h[k];
    }
#pragma unroll
    for (int k = 0; k < 16; k += 2) {
      f16x2 v; v.x = (f16)h[k]; v.y = (f16)h[k + 1];
      *(f16x2*)(hbuf + hm * 136 + hf + k) = v;
      if (x2h) *(f16x2*)(x2h + (size_t)(t * 32 + hm) * 128 + hf + k) = v;
    }
    __syncthreads();
  }
}

__global__ __launch_bounds__(256, 1) void gru_persist(
    const f16* __restrict__ gp, const float* __restrict__ gi0, float* __restrict__ gi1,
    f16* __restrict__ x2h,
    const float* __restrict__ bih0, const float* __restrict__ bhh0,
    const float* __restrict__ bih1, const float* __restrict__ bhh1,
    const float* __restrict__ Wc, const float* __restrict__ bc,
    float* __restrict__ out) {
  __shared__ float ghbuf[32 * GH_ST];           // 51.2 KB
  __shared__ f16 hbuf[32 * 136];                // 8.7 KB
  int tid = threadIdx.x, wave = tid >> 6, lane = tid & 63;
  int quad = lane >> 4, mm = lane & 15;
  int hm = tid >> 3, hf = (tid & 7) * 16;
  float h[16];

  // ---- Phase 1: layer-0 recurrence (Whh0 = mat 1), writes x2h ----
  recurrence_phase(gp + 1 * 49152, gi0, bih0, bhh0, x2h, h, ghbuf, hbuf);
  __threadfence();
  __syncthreads();

  // ---- Phase 2: gi1 = x2 @ Wih1^T (mat 2), batched over all 256 rows ----
  {
    f16x8 B[24];
    load_bfrags(gp + 2 * 49152, wave, lane, B);
    for (int mt = 0; mt < 16; ++mt) {
      floatx4 acc[6];
#pragma unroll
      for (int i = 0; i < 6; ++i) { floatx4 z = {0.f, 0.f, 0.f, 0.f}; acc[i] = z; }
#pragma unroll
      for (int kc = 0; kc < 4; ++kc) {
        f16x8 a = *(const f16x8*)(x2h + (size_t)(mt * 16 + mm) * 128 + kc * 32 + quad * 8);
#pragma unroll
        for (int i = 0; i < 6; ++i)
          acc[i] = __builtin_amdgcn_mfma_f32_16x16x32_f16(a, B[i * 4 + kc], acc[i], 0, 0, 0);
      }
#pragma unroll
      for (int i = 0; i < 6; ++i)
#pragma unroll
        for (int r = 0; r < 4; ++r)
          gi1[(size_t)(mt * 16 + quad * 4 + r) * 384 + wave * 96 + i * 16 + mm] = acc[i][r];
    }
  }
  __threadfence();
  __syncthreads();

  // ---- Phase 3: layer-1 recurrence (Whh1 = mat 3) ----
  recurrence_phase(gp + 3 * 49152, gi1, bih1, bhh1, (f16*)nullptr, h, ghbuf, hbuf);

  // ---- final: out = h2 @ Wc^T + bc ----
  // stage h2 fp32 into ghbuf[32][128]
#pragma unroll
  for (int k = 0; k < 16; ++k) ghbuf[hm * 128 + hf + k] = h[k];
  __syncthreads();
  // NOTE: G_*C_ = 320 > blockDim (256) -> strided loop (R3 bug: `if (tid<320)`
  // left out[256..319] unwritten)
  for (int o = tid; o < G_ * C_; o += 256) {
    int g = o / C_, c = o - g * C_;
    float s = bc[c];
    const float* wr = Wc + (size_t)c * 128;
    for (int k = 0; k < 128; k += 4) {
      float4 w = *(const float4*)(wr + k);
      s += ghbuf[g * 128 + k] * w.x + ghbuf[g * 128 + k + 1] * w.y +
           ghbuf[g * 128 + k + 2] * w.z + ghbuf[g * 128 + k + 3] * w.w;
    }
    out[o] = s;
  }
}

extern "C" void kernel_launch(void* const* d_in, const int* in_sizes, int n_in,
                              void* d_out, int out_size, void* d_ws, size_t ws_size,
                              hipStream_t stream) {
  const float* x    = (const float*)d_in[0];
  const int*   ei   = (const int*)d_in[1];
  const int*   batch= (const int*)d_in[2];
  const float* W1   = (const float*)d_in[3];
  const float* b1   = (const float*)d_in[4];
  const float* W2   = (const float*)d_in[5];
  const float* b2   = (const float*)d_in[6];
  const float* Wih0 = (const float*)d_in[7];
  const float* Whh0 = (const float*)d_in[8];
  const float* bih0 = (const float*)d_in[9];
  const float* bhh0 = (const float*)d_in[10];
  const float* Wih1 = (const float*)d_in[11];
  const float* Whh1 = (const float*)d_in[12];
  const float* bih1 = (const float*)d_in[13];
  const float* bhh1 = (const float*)d_in[14];
  const float* Wc   = (const float*)d_in[15];
  const float* bc   = (const float*)d_in[16];
  float* out = (float*)d_out;

  char* ws = (char*)d_ws;
  f16*   Xh    = (f16*)(ws + OFF_XH);
  f16*   A1    = (f16*)(ws + OFF_A1);
  f16*   H1    = (f16*)(ws + OFF_H1);
  f16*   A2    = A1;                 // A1 dead after GEMM1
  f16*   H2    = Xh;                 // Xh dead after AGG1
  int*   col   = (int*)(ws + OFF_COL);
  float* coef  = (float*)(ws + OFF_COEF);
  int*   degI  = (int*)(ws + OFF_DEG);
  int*   fillc = (int*)(ws + OFF_FILL);
  int*   cntG  = (int*)(ws + OFF_CNTG);
  int*   fillb = (int*)(ws + OFF_FILLB);
  float* dinv  = (float*)(ws + OFF_DINV);
  int*   rp    = (int*)(ws + OFF_RP);
  f16*   Wp    = (f16*)(ws + OFF_WP);
  int*   brp   = (int*)(ws + OFF_BRP);
  int*   blist = (int*)(ws + OFF_BLIST);
  f16*   embh  = (f16*)(ws + OFF_EMBH);
  f16*   gp    = (f16*)(ws + OFF_GPACK);
  float* gi0   = (float*)(ws + OFF_GI0);
  float* gi1   = (float*)(ws + OFF_GI1);
  f16*   x2h   = (f16*)(ws + OFF_X2H);

  hipMemsetAsync(ws + OFF_DEG, 0, ZERO_BYTES, stream);

  cvt_kernel<<<10000, 256, 0, stream>>>(x, Xh);
  pack_kernel<<<128, 256, 0, stream>>>(W1, W2, Wp);
  gpack_kernel<<<768, 256, 0, stream>>>(Wih0, Whh0, Wih1, Whh1, gp);
  deg_kernel<<<5000, 256, 0, stream>>>(ei, degI);
  node_kernel<<<313, 256, 0, stream>>>(degI, dinv, batch, cntG);
  scan_kernel<<<8, 1024, 0, stream>>>(degI, rp);
  bscan_kernel<<<1, 256, 0, stream>>>(cntG, brp);
  fill_kernel<<<5000, 256, 0, stream>>>(ei, rp, fillc, dinv, col, coef);
  bfill_kernel<<<313, 256, 0, stream>>>(batch, brp, fillb, blist);

  agg_kernel<<<20000, 256, 0, stream>>>(Xh, A1, rp, col, coef, dinv);
  gemm_kernel<<<1250, 256, 0, stream>>>(A1, Wp, b1, H1);
  agg_kernel<<<20000, 256, 0, stream>>>(H1, A2, rp, col, coef, dinv);
  gemm_kernel<<<1250, 256, 0, stream>>>(A2, Wp + 16384, b2, H2);

  pool_kernel<<<64, 256, 0, stream>>>(H2, brp, blist, embh);
  gi0_kernel<<<4, 256, 0, stream>>>(embh, gp, gi0);
  gru_persist<<<1, 256, 0, stream>>>(gp, gi0, gi1, x2h, bih0, bhh0, bih1, bhh1,
                                     Wc, bc, out);
}

// Round 5
// 503.862 us; speedup vs baseline: 1.5676x; 1.1583x over previous
//
#include <hip/hip_runtime.h>

#define T_ 8
#define N_ 10000
#define E_ 160000
#define G_ 32
#define C_ 10
#define F_ 128

typedef _Float16 f16;
typedef _Float16 f16x2 __attribute__((ext_vector_type(2)));
typedef _Float16 f16x4 __attribute__((ext_vector_type(4)));
typedef _Float16 f16x8 __attribute__((ext_vector_type(8)));
typedef float floatx4 __attribute__((ext_vector_type(4)));

static constexpr size_t ROWS = (size_t)T_ * N_;   // 80000

// ---------------- workspace layout (bytes) ----------------
static constexpr size_t OFF_XH    = 0;          // f16 [80000][128] (reused as H2)
static constexpr size_t OFF_A1    = 20480000;   // f16 [80000][128] (reused as A2)
static constexpr size_t OFF_H1    = 40960000;   // f16 [80000][128]
static constexpr size_t OFF_COL   = 61440000;   // int [T][E]
static constexpr size_t OFF_COEF  = 66560000;   // float [T][E]
static constexpr size_t OFF_DEG   = 71680000;   // int [T][N]    -- zeroed
static constexpr size_t OFF_FILL  = 72000000;   // int [T][N]    -- zeroed
static constexpr size_t OFF_CNTG  = 72320000;   // int [T][G]    -- zeroed
static constexpr size_t OFF_FILLB = 72321024;   // int [T][G]    -- zeroed
static constexpr size_t ZERO_BYTES = 642048;    // DEG..FILLB contiguous
static constexpr size_t OFF_DINV  = 72322048;   // float [T][N]
static constexpr size_t OFF_RP    = 72642048;   // int [T][N+1]
static constexpr size_t OFF_WP    = 72962080;   // f16 packed W1,W2 (2*16384)
static constexpr size_t OFF_BRP   = 73027616;   // int [T*G+1]
static constexpr size_t OFF_BLIST = 73028648;   // int [80000]
static constexpr size_t OFF_EMBH  = 73348656;   // f16 [256][128]
static constexpr size_t OFF_GPACK = 73414192;   // f16 4*49152 packed GRU weights
static constexpr size_t OFF_GI0   = 73807408;   // float [256][384]
// end ~74.2 MB

// ---------------- fast gates (v_exp_f32 / v_rcp_f32, ~1 ulp) ----------------
__device__ __forceinline__ float sig_fast(float x) {
  return __builtin_amdgcn_rcpf(1.0f + __builtin_amdgcn_exp2f(-1.4426950408889634f * x));
}
__device__ __forceinline__ float tanh_fast(float x) {
  // tanh(x) = 1 - 2/(exp2(2x*log2e)+1); saturates correctly at +-inf
  return 1.0f - 2.0f * __builtin_amdgcn_rcpf(1.0f + __builtin_amdgcn_exp2f(2.8853900817779268f * x));
}

// ---------------- fp32 -> fp16 convert ----------------
__global__ void cvt_kernel(const float* __restrict__ x, f16* __restrict__ xh) {
  size_t i = ((size_t)blockIdx.x * 256 + threadIdx.x) * 4;
  float4 v = *(const float4*)(x + i);
  f16x4 o; o.x = (f16)v.x; o.y = (f16)v.y; o.z = (f16)v.z; o.w = (f16)v.w;
  *(f16x4*)(xh + i) = o;
}

// ---------------- degree histogram (by dst) ----------------
__global__ void deg_kernel(const int* __restrict__ ei, int* __restrict__ degI) {
  int gid = blockIdx.x * 256 + threadIdx.x;     // exactly T*E
  int t = gid / E_, e = gid - t * E_;
  int dst = ei[(size_t)t * 2 * E_ + E_ + e];
  atomicAdd(&degI[t * N_ + dst], 1);
}

// ---------------- per-node: dinv + group counts ----------------
__global__ void node_kernel(const int* __restrict__ degI, float* __restrict__ dinv,
                            const int* __restrict__ batch, int* __restrict__ cntG) {
  int gid = blockIdx.x * 256 + threadIdx.x;
  if (gid < (int)ROWS) {
    dinv[gid] = rsqrtf((float)degI[gid] + 1.0f);
    atomicAdd(&cntG[(gid / N_) * G_ + batch[gid]], 1);
  }
}

// ---------------- per-t exclusive scan of deg -> row_ptr ----------------
__global__ void scan_kernel(const int* __restrict__ degI, int* __restrict__ rp) {
  __shared__ int wsum[16];
  __shared__ int carry;
  int t = blockIdx.x, tid = threadIdx.x, lane = tid & 63, wid = tid >> 6;
  if (tid == 0) { carry = 0; rp[t * (N_ + 1)] = 0; }
  __syncthreads();
  const int* d = degI + t * N_;
  int* r = rp + t * (N_ + 1);
  for (int c0 = 0; c0 < N_; c0 += 1024) {
    int i = c0 + tid;
    int v = (i < N_) ? d[i] : 0;
    for (int ofs = 1; ofs < 64; ofs <<= 1) {
      int u = __shfl_up(v, ofs);
      if (lane >= ofs) v += u;
    }
    if (lane == 63) wsum[wid] = v;
    __syncthreads();
    if (wid == 0) {
      int w = (lane < 16) ? wsum[lane] : 0;
      for (int ofs = 1; ofs < 16; ofs <<= 1) {
        int u = __shfl_up(w, ofs);
        if (lane >= ofs) w += u;
      }
      if (lane < 16) wsum[lane] = w;
    }
    __syncthreads();
    int base = carry + (wid ? wsum[wid - 1] : 0);
    if (i < N_) r[i + 1] = v + base;
    __syncthreads();
    if (tid == 0) carry += wsum[15];
    __syncthreads();
  }
}

// ---------------- tiny scan over [T*G] group counts -> brp ----------------
__global__ void bscan_kernel(const int* __restrict__ cntG, int* __restrict__ brp) {
  __shared__ int ws[4];
  int tid = threadIdx.x, lane = tid & 63, wid = tid >> 6;
  int v = cntG[tid];
  for (int ofs = 1; ofs < 64; ofs <<= 1) {
    int u = __shfl_up(v, ofs);
    if (lane >= ofs) v += u;
  }
  if (lane == 63) ws[wid] = v;
  __syncthreads();
  int base = 0;
  for (int w = 0; w < wid; ++w) base += ws[w];
  if (tid == 0) brp[0] = 0;
  brp[tid + 1] = v + base;
}

// ---------------- CSR fill: col (src) + coef ----------------
__global__ void fill_kernel(const int* __restrict__ ei, const int* __restrict__ rp,
                            int* __restrict__ fillc, const float* __restrict__ dinv,
                            int* __restrict__ col, float* __restrict__ coef) {
  int gid = blockIdx.x * 256 + threadIdx.x;     // exactly T*E
  int t = gid / E_, e = gid - t * E_;
  int src = ei[(size_t)t * 2 * E_ + e];
  int dst = ei[(size_t)t * 2 * E_ + E_ + e];
  int pos = rp[t * (N_ + 1) + dst] + atomicAdd(&fillc[t * N_ + dst], 1);
  col[(size_t)t * E_ + pos]  = src;
  coef[(size_t)t * E_ + pos] = dinv[t * N_ + src] * dinv[t * N_ + dst];
}

// ---------------- batch-CSR fill: node lists per (t,g) ----------------
__global__ void bfill_kernel(const int* __restrict__ batch, const int* __restrict__ brp,
                             int* __restrict__ fillb, int* __restrict__ blist) {
  int gid = blockIdx.x * 256 + threadIdx.x;
  if (gid < (int)ROWS) {
    int t = gid / N_;
    int g = batch[gid];
    int pos = brp[t * G_ + g] + atomicAdd(&fillb[t * G_ + g], 1);
    blist[pos] = gid;                           // global row id
  }
}

// ---------------- aggregation (XCD-swizzled, unroll-4) ----------------
__global__ void agg_kernel(const f16* __restrict__ X, f16* __restrict__ A,
                           const int* __restrict__ rp, const int* __restrict__ col,
                           const float* __restrict__ coef, const float* __restrict__ dinv) {
  int wave = threadIdx.x >> 6, lane = threadIdx.x & 63;
  int b = blockIdx.x;
  int t = b & 7, i = b >> 3;
  int n = i * 4 + wave;
  int row = t * N_ + n;
  float ds = dinv[row]; ds *= ds;
  f16x2 xv = *(const f16x2*)(X + (size_t)row * F_ + 2 * lane);
  float a00 = ds * (float)xv.x, a01 = ds * (float)xv.y;
  float a10 = 0.f, a11 = 0.f, a20 = 0.f, a21 = 0.f, a30 = 0.f, a31 = 0.f;
  int beg = rp[t * (N_ + 1) + n], end = rp[t * (N_ + 1) + n + 1];
  beg = __builtin_amdgcn_readfirstlane(beg);
  end = __builtin_amdgcn_readfirstlane(end);
  const int*   cl = col  + (size_t)t * E_;
  const float* cf = coef + (size_t)t * E_;
  const f16*   Xt = X + (size_t)t * N_ * F_;
  int e = beg;
  for (; e + 3 < end; e += 4) {
    int s0 = cl[e], s1 = cl[e + 1], s2 = cl[e + 2], s3 = cl[e + 3];
    float c0 = cf[e], c1 = cf[e + 1], c2 = cf[e + 2], c3 = cf[e + 3];
    f16x2 h0 = *(const f16x2*)(Xt + (size_t)s0 * F_ + 2 * lane);
    f16x2 h1 = *(const f16x2*)(Xt + (size_t)s1 * F_ + 2 * lane);
    f16x2 h2 = *(const f16x2*)(Xt + (size_t)s2 * F_ + 2 * lane);
    f16x2 h3 = *(const f16x2*)(Xt + (size_t)s3 * F_ + 2 * lane);
    a00 += c0 * (float)h0.x; a01 += c0 * (float)h0.y;
    a10 += c1 * (float)h1.x; a11 += c1 * (float)h1.y;
    a20 += c2 * (float)h2.x; a21 += c2 * (float)h2.y;
    a30 += c3 * (float)h3.x; a31 += c3 * (float)h3.y;
  }
  for (; e < end; ++e) {
    int s = cl[e]; float c = cf[e];
    f16x2 hv = *(const f16x2*)(Xt + (size_t)s * F_ + 2 * lane);
    a00 += c * (float)hv.x; a01 += c * (float)hv.y;
  }
  float r0 = (a00 + a10) + (a20 + a30);
  float r1 = (a01 + a11) + (a21 + a31);
  f16x2 o; o.x = (f16)r0; o.y = (f16)r1;
  *(f16x2*)(A + (size_t)row * F_ + 2 * lane) = o;
}

// ---------------- pack W1/W2 into MFMA B-fragment layout (f16) ----------------
__global__ void pack_kernel(const float* __restrict__ W1, const float* __restrict__ W2,
                            f16* __restrict__ Wp) {
  int idx = blockIdx.x * 256 + threadIdx.x;     // < 32768
  const float* W = (idx < 16384) ? W1 : W2;
  int l = idx & 16383;
  int j = l & 7, lane = (l >> 3) & 63, ct = (l >> 9) & 7, kc = (l >> 12) & 3;
  int k = kc * 32 + ((lane >> 4) & 3) * 8 + j;
  int n = ct * 16 + (lane & 15);
  Wp[idx] = (f16)W[k * 128 + n];
}

// ---------------- pack GRU weights [384][128] -> B-frag layout, B[k][u]=W[u][k] ----------------
// storage: (((mat*24 + nt)*4 + kc)*64 + lane)*8 + j ; k=kc*32+(lane>>4)*8+j ; u=nt*16+(lane&15)
__global__ void gpack_kernel(const float* __restrict__ A0, const float* __restrict__ A1,
                             const float* __restrict__ A2, const float* __restrict__ A3,
                             f16* __restrict__ gp) {
  int idx = blockIdx.x * 256 + threadIdx.x;     // < 196608
  int mat = idx / 49152, l = idx - mat * 49152;
  int j = l & 7, lane = (l >> 3) & 63, kc = (l >> 9) & 3, nt = l >> 11;
  int k = kc * 32 + ((lane >> 4) & 3) * 8 + j;
  int u = nt * 16 + (lane & 15);
  const float* W = (mat == 0) ? A0 : (mat == 1) ? A1 : (mat == 2) ? A2 : A3;
  gp[idx] = (f16)W[u * 128 + k];
}

// ---------------- GEMM: O = relu(A @ W + b), MFMA 16x16x32 ----------------
__global__ __launch_bounds__(256) void gemm_kernel(const f16* __restrict__ A,
                                                   const f16* __restrict__ Wp,
                                                   const float* __restrict__ bias,
                                                   f16* __restrict__ O) {
  __shared__ f16x8 Bp[2048];                    // 32 KB packed W
  const f16x8* Wv = (const f16x8*)Wp;
  for (int i = threadIdx.x; i < 2048; i += 256) Bp[i] = Wv[i];
  __syncthreads();
  int wave = threadIdx.x >> 6, lane = threadIdx.x & 63;
  int quad = lane >> 4, m = lane & 15;
  int rowbase = blockIdx.x * 64 + wave * 16;
  const f16x8* Arow = (const f16x8*)(A + (size_t)(rowbase + m) * F_);
  floatx4 acc[8];
#pragma unroll
  for (int ct = 0; ct < 8; ++ct) { floatx4 z = {0.f, 0.f, 0.f, 0.f}; acc[ct] = z; }
#pragma unroll
  for (int kc = 0; kc < 4; ++kc) {
    f16x8 a = Arow[kc * 4 + quad];
#pragma unroll
    for (int ct = 0; ct < 8; ++ct)
      acc[ct] = __builtin_amdgcn_mfma_f32_16x16x32_f16(a, Bp[(kc * 8 + ct) * 64 + lane],
                                                       acc[ct], 0, 0, 0);
  }
#pragma unroll
  for (int ct = 0; ct < 8; ++ct) {
    int colc = ct * 16 + m;
    float bv = bias[colc];
#pragma unroll
    for (int r = 0; r < 4; ++r) {
      int row = rowbase + quad * 4 + r;
      float v = acc[ct][r] + bv;
      O[(size_t)row * F_ + colc] = (f16)fmaxf(v, 0.0f);
    }
  }
}

// ---------------- pooling via batch-CSR gather -> f16 emb ----------------
__global__ void pool_kernel(const f16* __restrict__ H, const int* __restrict__ brp,
                            const int* __restrict__ blist, f16* __restrict__ embh) {
  int wave = threadIdx.x >> 6, lane = threadIdx.x & 63;
  int idx = blockIdx.x * 4 + wave;              // t*G+g, < 256
  int beg = brp[idx], end = brp[idx + 1];
  beg = __builtin_amdgcn_readfirstlane(beg);
  end = __builtin_amdgcn_readfirstlane(end);
  float a00 = 0.f, a01 = 0.f, a10 = 0.f, a11 = 0.f;
  float a20 = 0.f, a21 = 0.f, a30 = 0.f, a31 = 0.f;
  int e = beg;
  for (; e + 3 < end; e += 4) {
    int r0 = blist[e], r1 = blist[e + 1], r2 = blist[e + 2], r3 = blist[e + 3];
    f16x2 v0 = *(const f16x2*)(H + (size_t)r0 * F_ + 2 * lane);
    f16x2 v1 = *(const f16x2*)(H + (size_t)r1 * F_ + 2 * lane);
    f16x2 v2 = *(const f16x2*)(H + (size_t)r2 * F_ + 2 * lane);
    f16x2 v3 = *(const f16x2*)(H + (size_t)r3 * F_ + 2 * lane);
    a00 += (float)v0.x; a01 += (float)v0.y;
    a10 += (float)v1.x; a11 += (float)v1.y;
    a20 += (float)v2.x; a21 += (float)v2.y;
    a30 += (float)v3.x; a31 += (float)v3.y;
  }
  for (; e < end; ++e) {
    int r = blist[e];
    f16x2 v = *(const f16x2*)(H + (size_t)r * F_ + 2 * lane);
    a00 += (float)v.x; a01 += (float)v.y;
  }
  float d = 1.0f / fmaxf((float)(end - beg), 1.0f);
  f16x2 o;
  o.x = (f16)(((a00 + a10) + (a20 + a30)) * d);
  o.y = (f16)(((a01 + a11) + (a21 + a31)) * d);
  *(f16x2*)(embh + (size_t)idx * F_ + 2 * lane) = o;
}

// ---------------- gi0 = emb @ Wih0^T : M=256, K=128, N=384 ----------------
__global__ __launch_bounds__(256) void gi0_kernel(const f16* __restrict__ embh,
                                                  const f16* __restrict__ gp,
                                                  float* __restrict__ gi0) {
  int wave = threadIdx.x >> 6, lane = threadIdx.x & 63;
  int quad = lane >> 4, mm = lane & 15;
  int rowbase = blockIdx.x * 64 + wave * 16;    // grid 4
  const f16* Arow = embh + (size_t)(rowbase + mm) * 128;
  floatx4 acc[24];
#pragma unroll
  for (int nt = 0; nt < 24; ++nt) { floatx4 z = {0.f, 0.f, 0.f, 0.f}; acc[nt] = z; }
#pragma unroll
  for (int kc = 0; kc < 4; ++kc) {
    f16x8 a = *(const f16x8*)(Arow + kc * 32 + quad * 8);
#pragma unroll
    for (int nt = 0; nt < 24; ++nt) {
      f16x8 b = *(const f16x8*)(gp + (size_t)(((nt * 4 + kc) * 64 + lane)) * 8);
      acc[nt] = __builtin_amdgcn_mfma_f32_16x16x32_f16(a, b, acc[nt], 0, 0, 0);
    }
  }
#pragma unroll
  for (int nt = 0; nt < 24; ++nt)
#pragma unroll
    for (int r = 0; r < 4; ++r)
      gi0[(size_t)(rowbase + quad * 4 + r) * 384 + nt * 16 + mm] = acc[nt][r];
}

// ---------------- fused 2-layer GRU + final linear: 16 blocks x 2 groups ----------------
// Whh0/Whh1 B-frags resident in VGPRs; Wih1 streamed from L2 per step (prefetched).
// h-state fp32 in regs (thread (g2,f) owns h[g2][f]); f16 mirror in LDS rows 0-1 of a
// 16-row MFMA A buffer (rows 2-15 zero). Layers fused per timestep -> no global sync.
__global__ __launch_bounds__(256, 1) void gru_fused(
    const f16* __restrict__ gp, const float* __restrict__ gi0,
    const float* __restrict__ bih0, const float* __restrict__ bhh0,
    const float* __restrict__ bih1, const float* __restrict__ bhh1,
    const float* __restrict__ Wc, const float* __restrict__ bc,
    float* __restrict__ out) {
  __shared__ f16 hb0[16 * 136];                 // layer-0 h (== x2 after update), rows 0-1 live
  __shared__ f16 hb1[16 * 136];                 // layer-1 h
  __shared__ float ghb[2 * 384];                // gh0 then gh1
  __shared__ float gib[2 * 384];                // gi1
  __shared__ float h1s[2 * 128];                // final h1 staging (fp32)
  int tid = threadIdx.x, wave = tid >> 6, lane = tid & 63;
  int quad = lane >> 4, mm = lane & 15;
  int g2 = tid >> 7, f = tid & 127;
  int bid = blockIdx.x;

  // resident B-frags: Whh0 (mat 1), Whh1 (mat 3) -- wave owns col-tiles nt=wave*6..+5
  f16x8 B0[24], B1[24];
#pragma unroll
  for (int i = 0; i < 6; ++i)
#pragma unroll
    for (int kc = 0; kc < 4; ++kc) {
      size_t off = (size_t)((((wave * 6 + i) * 4 + kc) * 64 + lane)) * 8;
      B0[i * 4 + kc] = *(const f16x8*)(gp + 1 * 49152 + off);
      B1[i * 4 + kc] = *(const f16x8*)(gp + 3 * 49152 + off);
    }
  // combined biases for thread's gate element f
  float br0 = bih0[f] + bhh0[f];
  float bz0 = bih0[128 + f] + bhh0[128 + f];
  float bni0 = bih0[256 + f], bnh0 = bhh0[256 + f];
  float br1 = bih1[f] + bhh1[f];
  float bz1 = bih1[128 + f] + bhh1[128 + f];
  float bni1 = bih1[256 + f], bnh1 = bhh1[256 + f];

  for (int i = tid; i < 16 * 136; i += 256) { hb0[i] = (f16)0.f; hb1[i] = (f16)0.f; }
  float h0 = 0.f, h1 = 0.f;
  __syncthreads();

  const f16* wih1 = gp + 2 * 49152;
  for (int t = 0; t < T_; ++t) {
    // prefetch streamed Wih1 B-frags + this step's gi0 slice (consumed after Pass A)
    f16x8 Bs[24];
#pragma unroll
    for (int i = 0; i < 6; ++i)
#pragma unroll
      for (int kc = 0; kc < 4; ++kc)
        Bs[i * 4 + kc] = *(const f16x8*)(wih1 +
            (size_t)((((wave * 6 + i) * 4 + kc) * 64 + lane)) * 8);
    const float* gi = gi0 + (size_t)(t * G_ + bid * 2 + g2) * 384;
    float gir = gi[f], giz = gi[128 + f], gin = gi[256 + f];

    // ---- Pass A: gh0 = h0 @ Whh0^T (rows 0-1 of M=16) ----
    floatx4 acc[6];
#pragma unroll
    for (int i = 0; i < 6; ++i) { floatx4 z = {0.f, 0.f, 0.f, 0.f}; acc[i] = z; }
#pragma unroll
    for (int kc = 0; kc < 4; ++kc) {
      f16x8 a = *(const f16x8*)(hb0 + mm * 136 + kc * 32 + quad * 8);
#pragma unroll
      for (int i = 0; i < 6; ++i)
        acc[i] = __builtin_amdgcn_mfma_f32_16x16x32_f16(a, B0[i * 4 + kc], acc[i], 0, 0, 0);
    }
    if (quad == 0) {                            // D rows 0,1 = (quad 0, reg 0/1)
#pragma unroll
      for (int i = 0; i < 6; ++i) {
        ghb[0 * 384 + wave * 96 + i * 16 + mm] = acc[i][0];
        ghb[1 * 384 + wave * 96 + i * 16 + mm] = acc[i][1];
      }
    }
    __syncthreads();

    // ---- gates layer 0 ----
    {
      float hr = ghb[g2 * 384 + f];
      float hz = ghb[g2 * 384 + 128 + f];
      float hn = ghb[g2 * 384 + 256 + f];
      float r = sig_fast(gir + hr + br0);
      float z = sig_fast(giz + hz + bz0);
      float nn = tanh_fast(gin + bni0 + r * (hn + bnh0));
      h0 = (1.0f - z) * nn + z * h0;
      hb0[g2 * 136 + f] = (f16)h0;              // becomes x2 for Pass B & next-step A
    }
    __syncthreads();

    // ---- Pass B: gi1 = x2 @ Wih1^T (Bs) and gh1 = h1 @ Whh1^T (B1) ----
    floatx4 accx[6], acch[6];
#pragma unroll
    for (int i = 0; i < 6; ++i) {
      floatx4 z = {0.f, 0.f, 0.f, 0.f}; accx[i] = z; acch[i] = z;
    }
#pragma unroll
    for (int kc = 0; kc < 4; ++kc) {
      f16x8 ax = *(const f16x8*)(hb0 + mm * 136 + kc * 32 + quad * 8);
      f16x8 ah = *(const f16x8*)(hb1 + mm * 136 + kc * 32 + quad * 8);
#pragma unroll
      for (int i = 0; i < 6; ++i) {
        accx[i] = __builtin_amdgcn_mfma_f32_16x16x32_f16(ax, Bs[i * 4 + kc], accx[i], 0, 0, 0);
        acch[i] = __builtin_amdgcn_mfma_f32_16x16x32_f16(ah, B1[i * 4 + kc], acch[i], 0, 0, 0);
      }
    }
    if (quad == 0) {
#pragma unroll
      for (int i = 0; i < 6; ++i) {
        gib[0 * 384 + wave * 96 + i * 16 + mm] = accx[i][0];
        gib[1 * 384 + wave * 96 + i * 16 + mm] = accx[i][1];
        ghb[0 * 384 + wave * 96 + i * 16 + mm] = acch[i][0];
        ghb[1 * 384 + wave * 96 + i * 16 + mm] = acch[i][1];
      }
    }
    __syncthreads();

    // ---- gates layer 1 ----
    {
      float i1r = gib[g2 * 384 + f];
      float i1z = gib[g2 * 384 + 128 + f];
      float i1n = gib[g2 * 384 + 256 + f];
      float hr = ghb[g2 * 384 + f];
      float hz = ghb[g2 * 384 + 128 + f];
      float hn = ghb[g2 * 384 + 256 + f];
      float r = sig_fast(i1r + hr + br1);
      float z = sig_fast(i1z + hz + bz1);
      float nn = tanh_fast(i1n + bni1 + r * (hn + bnh1));
      h1 = (1.0f - z) * nn + z * h1;
      hb1[g2 * 136 + f] = (f16)h1;
    }
    __syncthreads();
  }

  // ---- final: out[g] = h1 @ Wc^T + bc for this block's 2 groups ----
  h1s[g2 * 128 + f] = h1;
  __syncthreads();
  if (tid < 2 * C_) {
    int gg = tid / C_, c = tid - gg * C_;
    float s = bc[c];
    const float* wr = Wc + (size_t)c * 128;
    const float* hr = h1s + gg * 128;
    for (int k = 0; k < 128; k += 4) {
      float4 w = *(const float4*)(wr + k);
      s += hr[k] * w.x + hr[k + 1] * w.y + hr[k + 2] * w.z + hr[k + 3] * w.w;
    }
    out[(bid * 2 + gg) * C_ + c] = s;
  }
}

extern "C" void kernel_launch(void* const* d_in, const int* in_sizes, int n_in,
                              void* d_out, int out_size, void* d_ws, size_t ws_size,
                              hipStream_t stream) {
  const float* x    = (const float*)d_in[0];
  const int*   ei   = (const int*)d_in[1];
  const int*   batch= (const int*)d_in[2];
  const float* W1   = (const float*)d_in[3];
  const float* b1   = (const float*)d_in[4];
  const float* W2   = (const float*)d_in[5];
  const float* b2   = (const float*)d_in[6];
  const float* Wih0 = (const float*)d_in[7];
  const float* Whh0 = (const float*)d_in[8];
  const float* bih0 = (const float*)d_in[9];
  const float* bhh0 = (const float*)d_in[10];
  const float* Wih1 = (const float*)d_in[11];
  const float* Whh1 = (const float*)d_in[12];
  const float* bih1 = (const float*)d_in[13];
  const float* bhh1 = (const float*)d_in[14];
  const float* Wc   = (const float*)d_in[15];
  const float* bc   = (const float*)d_in[16];
  float* out = (float*)d_out;

  char* ws = (char*)d_ws;
  f16*   Xh    = (f16*)(ws + OFF_XH);
  f16*   A1    = (f16*)(ws + OFF_A1);
  f16*   H1    = (f16*)(ws + OFF_H1);
  f16*   A2    = A1;                 // A1 dead after GEMM1
  f16*   H2    = Xh;                 // Xh dead after AGG1
  int*   col   = (int*)(ws + OFF_COL);
  float* coef  = (float*)(ws + OFF_COEF);
  int*   degI  = (int*)(ws + OFF_DEG);
  int*   fillc = (int*)(ws + OFF_FILL);
  int*   cntG  = (int*)(ws + OFF_CNTG);
  int*   fillb = (int*)(ws + OFF_FILLB);
  float* dinv  = (float*)(ws + OFF_DINV);
  int*   rp    = (int*)(ws + OFF_RP);
  f16*   Wp    = (f16*)(ws + OFF_WP);
  int*   brp   = (int*)(ws + OFF_BRP);
  int*   blist = (int*)(ws + OFF_BLIST);
  f16*   embh  = (f16*)(ws + OFF_EMBH);
  f16*   gp    = (f16*)(ws + OFF_GPACK);
  float* gi0   = (float*)(ws + OFF_GI0);

  hipMemsetAsync(ws + OFF_DEG, 0, ZERO_BYTES, stream);

  cvt_kernel<<<10000, 256, 0, stream>>>(x, Xh);
  pack_kernel<<<128, 256, 0, stream>>>(W1, W2, Wp);
  gpack_kernel<<<768, 256, 0, stream>>>(Wih0, Whh0, Wih1, Whh1, gp);
  deg_kernel<<<5000, 256, 0, stream>>>(ei, degI);
  node_kernel<<<313, 256, 0, stream>>>(degI, dinv, batch, cntG);
  scan_kernel<<<8, 1024, 0, stream>>>(degI, rp);
  bscan_kernel<<<1, 256, 0, stream>>>(cntG, brp);
  fill_kernel<<<5000, 256, 0, stream>>>(ei, rp, fillc, dinv, col, coef);
  bfill_kernel<<<313, 256, 0, stream>>>(batch, brp, fillb, blist);

  agg_kernel<<<20000, 256, 0, stream>>>(Xh, A1, rp, col, coef, dinv);
  gemm_kernel<<<1250, 256, 0, stream>>>(A1, Wp, b1, H1);
  agg_kernel<<<20000, 256, 0, stream>>>(H1, A2, rp, col, coef, dinv);
  gemm_kernel<<<1250, 256, 0, stream>>>(A2, Wp + 16384, b2, H2);

  pool_kernel<<<64, 256, 0, stream>>>(H2, brp, blist, embh);
  gi0_kernel<<<4, 256, 0, stream>>>(embh, gp, gi0);
  gru_fused<<<16, 256, 0, stream>>>(gp, gi0, bih0, bhh0, bih1, bhh1, Wc, bc, out);
}

// Round 6
// 488.127 us; speedup vs baseline: 1.6181x; 1.0322x over previous
//
#include <hip/hip_runtime.h>

#define T_ 8
#define N_ 10000
#define E_ 160000
#define G_ 32
#define C_ 10
#define F_ 128

typedef _Float16 f16;
typedef _Float16 f16x2 __attribute__((ext_vector_type(2)));
typedef _Float16 f16x4 __attribute__((ext_vector_type(4)));
typedef _Float16 f16x8 __attribute__((ext_vector_type(8)));
typedef float floatx4 __attribute__((ext_vector_type(4)));

static constexpr size_t ROWS = (size_t)T_ * N_;   // 80000

// ---------------- workspace layout (bytes) ----------------
static constexpr size_t OFF_XH    = 0;          // f16 [80000][128] (reused as H2)
static constexpr size_t OFF_A1    = 20480000;   // f16 [80000][128] (reused as A2)
static constexpr size_t OFF_H1    = 40960000;   // f16 [80000][128]
static constexpr size_t OFF_REC   = 61440000;   // int2 [T][E]  (src, coef-bits)
static constexpr size_t OFF_DEG   = 71680000;   // int [T][N]    -- zeroed
static constexpr size_t OFF_FILL  = 72000000;   // int [T][N]    -- zeroed
static constexpr size_t OFF_CNTG  = 72320000;   // int [T][G]    -- zeroed
static constexpr size_t OFF_FILLB = 72321024;   // int [T][G]    -- zeroed
static constexpr size_t ZERO_BYTES = 642048;    // DEG..FILLB contiguous
static constexpr size_t OFF_DINV  = 72322048;   // float [T][N]
static constexpr size_t OFF_RP    = 72642048;   // int [T][N+1]
static constexpr size_t OFF_WP    = 72962080;   // f16 packed W1,W2 (2*16384)
static constexpr size_t OFF_BRP   = 73027616;   // int [T*G+1]
static constexpr size_t OFF_BLIST = 73028648;   // int [80000]
static constexpr size_t OFF_EMBH  = 73348656;   // f16 [256][128]
static constexpr size_t OFF_GPACK = 73414192;   // f16 4*49152 packed GRU weights
static constexpr size_t OFF_GI0   = 73807408;   // float [256][384]
// end ~74.2 MB

// ---------------- fast gates (v_exp_f32 / v_rcp_f32, ~1 ulp) ----------------
__device__ __forceinline__ float sig_fast(float x) {
  return __builtin_amdgcn_rcpf(1.0f + __builtin_amdgcn_exp2f(-1.4426950408889634f * x));
}
__device__ __forceinline__ float tanh_fast(float x) {
  return 1.0f - 2.0f * __builtin_amdgcn_rcpf(1.0f + __builtin_amdgcn_exp2f(2.8853900817779268f * x));
}

// ---------------- fp32 -> fp16 convert ----------------
__global__ void cvt_kernel(const float* __restrict__ x, f16* __restrict__ xh) {
  size_t i = ((size_t)blockIdx.x * 256 + threadIdx.x) * 4;
  float4 v = *(const float4*)(x + i);
  f16x4 o; o.x = (f16)v.x; o.y = (f16)v.y; o.z = (f16)v.z; o.w = (f16)v.w;
  *(f16x4*)(xh + i) = o;
}

// ---------------- degree histogram (by dst) ----------------
__global__ void deg_kernel(const int* __restrict__ ei, int* __restrict__ degI) {
  int gid = blockIdx.x * 256 + threadIdx.x;     // exactly T*E
  int t = gid / E_, e = gid - t * E_;
  int dst = ei[(size_t)t * 2 * E_ + E_ + e];
  atomicAdd(&degI[t * N_ + dst], 1);
}

// ---------------- per-node: dinv + group counts ----------------
__global__ void node_kernel(const int* __restrict__ degI, float* __restrict__ dinv,
                            const int* __restrict__ batch, int* __restrict__ cntG) {
  int gid = blockIdx.x * 256 + threadIdx.x;
  if (gid < (int)ROWS) {
    dinv[gid] = rsqrtf((float)degI[gid] + 1.0f);
    atomicAdd(&cntG[(gid / N_) * G_ + batch[gid]], 1);
  }
}

// ---------------- per-t exclusive scan of deg -> row_ptr; block 8 = group scan ----------------
__global__ void scan_kernel(const int* __restrict__ degI, int* __restrict__ rp,
                            const int* __restrict__ cntG, int* __restrict__ brp) {
  __shared__ int wsum[16];
  __shared__ int carry;
  int t = blockIdx.x, tid = threadIdx.x, lane = tid & 63, wid = tid >> 6;
  if (t == 8) {                                  // tiny scan over T*G group counts
    int v = (tid < 256) ? cntG[tid] : 0;
    for (int ofs = 1; ofs < 64; ofs <<= 1) {
      int u = __shfl_up(v, ofs);
      if (lane >= ofs) v += u;
    }
    if (lane == 63 && wid < 4) wsum[wid] = v;
    __syncthreads();
    if (tid < 256) {
      int base = 0;
      for (int w = 0; w < wid; ++w) base += wsum[w];
      if (tid == 0) brp[0] = 0;
      brp[tid + 1] = v + base;
    }
    return;
  }
  if (tid == 0) { carry = 0; rp[t * (N_ + 1)] = 0; }
  __syncthreads();
  const int* d = degI + t * N_;
  int* r = rp + t * (N_ + 1);
  for (int c0 = 0; c0 < N_; c0 += 1024) {
    int i = c0 + tid;
    int v = (i < N_) ? d[i] : 0;
    for (int ofs = 1; ofs < 64; ofs <<= 1) {
      int u = __shfl_up(v, ofs);
      if (lane >= ofs) v += u;
    }
    if (lane == 63) wsum[wid] = v;
    __syncthreads();
    if (wid == 0) {
      int w = (lane < 16) ? wsum[lane] : 0;
      for (int ofs = 1; ofs < 16; ofs <<= 1) {
        int u = __shfl_up(w, ofs);
        if (lane >= ofs) w += u;
      }
      if (lane < 16) wsum[lane] = w;
    }
    __syncthreads();
    int base = carry + (wid ? wsum[wid - 1] : 0);
    if (i < N_) r[i + 1] = v + base;
    __syncthreads();
    if (tid == 0) carry += wsum[15];
    __syncthreads();
  }
}

// ---------------- CSR fill (XCD-swizzled by t, combined 8B record) + batch-CSR fill ----------------
__global__ void fill_kernel(const int* __restrict__ ei, const int* __restrict__ rp,
                            int* __restrict__ fillc, const float* __restrict__ dinv,
                            int2* __restrict__ rec,
                            const int* __restrict__ batch, const int* __restrict__ brp,
                            int* __restrict__ fillb, int* __restrict__ blist) {
  int b = blockIdx.x;                           // 5000
  int t = b & 7, i = b >> 3;                    // 625 chunks per t
  int e = i * 256 + threadIdx.x;                // < E
  int src = ei[(size_t)t * 2 * E_ + e];
  int dst = ei[(size_t)t * 2 * E_ + E_ + e];
  int pos = rp[t * (N_ + 1) + dst] + atomicAdd(&fillc[t * N_ + dst], 1);
  int2 rv; rv.x = src; rv.y = __float_as_int(dinv[t * N_ + src] * dinv[t * N_ + dst]);
  rec[(size_t)t * E_ + pos] = rv;
  // fold former bfill_kernel into first 313 blocks
  int gid = b * 256 + threadIdx.x;
  if (gid < (int)ROWS) {
    int tt = gid / N_;
    int g = batch[gid];
    int p2 = brp[tt * G_ + g] + atomicAdd(&fillb[tt * G_ + g], 1);
    blist[p2] = gid;
  }
}

// ---------------- aggregation (XCD-swizzled, unroll-4, combined record) ----------------
__global__ void agg_kernel(const f16* __restrict__ X, f16* __restrict__ A,
                           const int* __restrict__ rp, const int2* __restrict__ rec,
                           const float* __restrict__ dinv) {
  int wave = threadIdx.x >> 6, lane = threadIdx.x & 63;
  int b = blockIdx.x;
  int t = b & 7, i = b >> 3;
  int n = i * 4 + wave;
  int row = t * N_ + n;
  float ds = dinv[row]; ds *= ds;
  f16x2 xv = *(const f16x2*)(X + (size_t)row * F_ + 2 * lane);
  float a00 = ds * (float)xv.x, a01 = ds * (float)xv.y;
  float a10 = 0.f, a11 = 0.f, a20 = 0.f, a21 = 0.f, a30 = 0.f, a31 = 0.f;
  int beg = rp[t * (N_ + 1) + n], end = rp[t * (N_ + 1) + n + 1];
  beg = __builtin_amdgcn_readfirstlane(beg);
  end = __builtin_amdgcn_readfirstlane(end);
  const int2* rc = rec + (size_t)t * E_;
  const f16*  Xt = X + (size_t)t * N_ * F_;
  int e = beg;
  for (; e + 3 < end; e += 4) {
    int2 r0 = rc[e], r1 = rc[e + 1], r2 = rc[e + 2], r3 = rc[e + 3];
    f16x2 h0 = *(const f16x2*)(Xt + (size_t)r0.x * F_ + 2 * lane);
    f16x2 h1 = *(const f16x2*)(Xt + (size_t)r1.x * F_ + 2 * lane);
    f16x2 h2 = *(const f16x2*)(Xt + (size_t)r2.x * F_ + 2 * lane);
    f16x2 h3 = *(const f16x2*)(Xt + (size_t)r3.x * F_ + 2 * lane);
    float c0 = __int_as_float(r0.y), c1 = __int_as_float(r1.y);
    float c2 = __int_as_float(r2.y), c3 = __int_as_float(r3.y);
    a00 += c0 * (float)h0.x; a01 += c0 * (float)h0.y;
    a10 += c1 * (float)h1.x; a11 += c1 * (float)h1.y;
    a20 += c2 * (float)h2.x; a21 += c2 * (float)h2.y;
    a30 += c3 * (float)h3.x; a31 += c3 * (float)h3.y;
  }
  for (; e < end; ++e) {
    int2 r = rc[e];
    float c = __int_as_float(r.y);
    f16x2 hv = *(const f16x2*)(Xt + (size_t)r.x * F_ + 2 * lane);
    a00 += c * (float)hv.x; a01 += c * (float)hv.y;
  }
  float r0 = (a00 + a10) + (a20 + a30);
  float r1 = (a01 + a11) + (a21 + a31);
  f16x2 o; o.x = (f16)r0; o.y = (f16)r1;
  *(f16x2*)(A + (size_t)row * F_ + 2 * lane) = o;
}

// ---------------- pack W1/W2 + GRU weights into MFMA B-frag layout (merged) ----------------
__global__ void packall_kernel(const float* __restrict__ W1, const float* __restrict__ W2,
                               f16* __restrict__ Wp,
                               const float* __restrict__ A0, const float* __restrict__ A1,
                               const float* __restrict__ A2, const float* __restrict__ A3,
                               f16* __restrict__ gp) {
  int idx = blockIdx.x * 256 + threadIdx.x;     // < 896*256 = 229376
  if (idx < 32768) {
    const float* W = (idx < 16384) ? W1 : W2;
    int l = idx & 16383;
    int j = l & 7, lane = (l >> 3) & 63, ct = (l >> 9) & 7, kc = (l >> 12) & 3;
    int k = kc * 32 + ((lane >> 4) & 3) * 8 + j;
    int n = ct * 16 + (lane & 15);
    Wp[idx] = (f16)W[k * 128 + n];
  } else {
    int gidx = idx - 32768;                     // < 196608
    int mat = gidx / 49152, l = gidx - mat * 49152;
    int j = l & 7, lane = (l >> 3) & 63, kc = (l >> 9) & 3, nt = l >> 11;
    int k = kc * 32 + ((lane >> 4) & 3) * 8 + j;
    int u = nt * 16 + (lane & 15);
    const float* W = (mat == 0) ? A0 : (mat == 1) ? A1 : (mat == 2) ? A2 : A3;
    gp[gidx] = (f16)W[u * 128 + k];
  }
}

// ---------------- GEMM: O = relu(A @ W + b), MFMA 16x16x32 ----------------
__global__ __launch_bounds__(256) void gemm_kernel(const f16* __restrict__ A,
                                                   const f16* __restrict__ Wp,
                                                   const float* __restrict__ bias,
                                                   f16* __restrict__ O) {
  __shared__ f16x8 Bp[2048];                    // 32 KB packed W
  const f16x8* Wv = (const f16x8*)Wp;
  for (int i = threadIdx.x; i < 2048; i += 256) Bp[i] = Wv[i];
  __syncthreads();
  int wave = threadIdx.x >> 6, lane = threadIdx.x & 63;
  int quad = lane >> 4, m = lane & 15;
  int rowbase = blockIdx.x * 64 + wave * 16;
  const f16x8* Arow = (const f16x8*)(A + (size_t)(rowbase + m) * F_);
  floatx4 acc[8];
#pragma unroll
  for (int ct = 0; ct < 8; ++ct) { floatx4 z = {0.f, 0.f, 0.f, 0.f}; acc[ct] = z; }
#pragma unroll
  for (int kc = 0; kc < 4; ++kc) {
    f16x8 a = Arow[kc * 4 + quad];
#pragma unroll
    for (int ct = 0; ct < 8; ++ct)
      acc[ct] = __builtin_amdgcn_mfma_f32_16x16x32_f16(a, Bp[(kc * 8 + ct) * 64 + lane],
                                                       acc[ct], 0, 0, 0);
  }
#pragma unroll
  for (int ct = 0; ct < 8; ++ct) {
    int colc = ct * 16 + m;
    float bv = bias[colc];
#pragma unroll
    for (int r = 0; r < 4; ++r) {
      int row = rowbase + quad * 4 + r;
      float v = acc[ct][r] + bv;
      O[(size_t)row * F_ + colc] = (f16)fmaxf(v, 0.0f);
    }
  }
}

// ---------------- pooling via batch-CSR gather -> f16 emb ----------------
__global__ void pool_kernel(const f16* __restrict__ H, const int* __restrict__ brp,
                            const int* __restrict__ blist, f16* __restrict__ embh) {
  int wave = threadIdx.x >> 6, lane = threadIdx.x & 63;
  int idx = blockIdx.x * 4 + wave;              // t*G+g, < 256
  int beg = brp[idx], end = brp[idx + 1];
  beg = __builtin_amdgcn_readfirstlane(beg);
  end = __builtin_amdgcn_readfirstlane(end);
  float a00 = 0.f, a01 = 0.f, a10 = 0.f, a11 = 0.f;
  float a20 = 0.f, a21 = 0.f, a30 = 0.f, a31 = 0.f;
  int e = beg;
  for (; e + 3 < end; e += 4) {
    int r0 = blist[e], r1 = blist[e + 1], r2 = blist[e + 2], r3 = blist[e + 3];
    f16x2 v0 = *(const f16x2*)(H + (size_t)r0 * F_ + 2 * lane);
    f16x2 v1 = *(const f16x2*)(H + (size_t)r1 * F_ + 2 * lane);
    f16x2 v2 = *(const f16x2*)(H + (size_t)r2 * F_ + 2 * lane);
    f16x2 v3 = *(const f16x2*)(H + (size_t)r3 * F_ + 2 * lane);
    a00 += (float)v0.x; a01 += (float)v0.y;
    a10 += (float)v1.x; a11 += (float)v1.y;
    a20 += (float)v2.x; a21 += (float)v2.y;
    a30 += (float)v3.x; a31 += (float)v3.y;
  }
  for (; e < end; ++e) {
    int r = blist[e];
    f16x2 v = *(const f16x2*)(H + (size_t)r * F_ + 2 * lane);
    a00 += (float)v.x; a01 += (float)v.y;
  }
  float d = 1.0f / fmaxf((float)(end - beg), 1.0f);
  f16x2 o;
  o.x = (f16)(((a00 + a10) + (a20 + a30)) * d);
  o.y = (f16)(((a01 + a11) + (a21 + a31)) * d);
  *(f16x2*)(embh + (size_t)idx * F_ + 2 * lane) = o;
}

// ---------------- gi0 = emb @ Wih0^T : M=256, K=128, N=384 ----------------
__global__ __launch_bounds__(256) void gi0_kernel(const f16* __restrict__ embh,
                                                  const f16* __restrict__ gp,
                                                  float* __restrict__ gi0) {
  int wave = threadIdx.x >> 6, lane = threadIdx.x & 63;
  int quad = lane >> 4, mm = lane & 15;
  int rowbase = blockIdx.x * 64 + wave * 16;    // grid 4
  const f16* Arow = embh + (size_t)(rowbase + mm) * 128;
  floatx4 acc[24];
#pragma unroll
  for (int nt = 0; nt < 24; ++nt) { floatx4 z = {0.f, 0.f, 0.f, 0.f}; acc[nt] = z; }
#pragma unroll
  for (int kc = 0; kc < 4; ++kc) {
    f16x8 a = *(const f16x8*)(Arow + kc * 32 + quad * 8);
#pragma unroll
    for (int nt = 0; nt < 24; ++nt) {
      f16x8 b = *(const f16x8*)(gp + (size_t)(((nt * 4 + kc) * 64 + lane)) * 8);
      acc[nt] = __builtin_amdgcn_mfma_f32_16x16x32_f16(a, b, acc[nt], 0, 0, 0);
    }
  }
#pragma unroll
  for (int nt = 0; nt < 24; ++nt)
#pragma unroll
    for (int r = 0; r < 4; ++r)
      gi0[(size_t)(rowbase + quad * 4 + r) * 384 + nt * 16 + mm] = acc[nt][r];
}

// ---------------- fused 2-layer GRU + final linear: 16 blocks x 2 groups ----------------
__global__ __launch_bounds__(256, 1) void gru_fused(
    const f16* __restrict__ gp, const float* __restrict__ gi0,
    const float* __restrict__ bih0, const float* __restrict__ bhh0,
    const float* __restrict__ bih1, const float* __restrict__ bhh1,
    const float* __restrict__ Wc, const float* __restrict__ bc,
    float* __restrict__ out) {
  __shared__ f16 hb0[16 * 136];
  __shared__ f16 hb1[16 * 136];
  __shared__ float ghb[2 * 384];
  __shared__ float gib[2 * 384];
  __shared__ float h1s[2 * 128];
  int tid = threadIdx.x, wave = tid >> 6, lane = tid & 63;
  int quad = lane >> 4, mm = lane & 15;
  int g2 = tid >> 7, f = tid & 127;
  int bid = blockIdx.x;

  f16x8 B0[24], B1[24];
#pragma unroll
  for (int i = 0; i < 6; ++i)
#pragma unroll
    for (int kc = 0; kc < 4; ++kc) {
      size_t off = (size_t)((((wave * 6 + i) * 4 + kc) * 64 + lane)) * 8;
      B0[i * 4 + kc] = *(const f16x8*)(gp + 1 * 49152 + off);
      B1[i * 4 + kc] = *(const f16x8*)(gp + 3 * 49152 + off);
    }
  float br0 = bih0[f] + bhh0[f];
  float bz0 = bih0[128 + f] + bhh0[128 + f];
  float bni0 = bih0[256 + f], bnh0 = bhh0[256 + f];
  float br1 = bih1[f] + bhh1[f];
  float bz1 = bih1[128 + f] + bhh1[128 + f];
  float bni1 = bih1[256 + f], bnh1 = bhh1[256 + f];

  for (int i = tid; i < 16 * 136; i += 256) { hb0[i] = (f16)0.f; hb1[i] = (f16)0.f; }
  float h0 = 0.f, h1 = 0.f;
  __syncthreads();

  const f16* wih1 = gp + 2 * 49152;
  for (int t = 0; t < T_; ++t) {
    f16x8 Bs[24];
#pragma unroll
    for (int i = 0; i < 6; ++i)
#pragma unroll
      for (int kc = 0; kc < 4; ++kc)
        Bs[i * 4 + kc] = *(const f16x8*)(wih1 +
            (size_t)((((wave * 6 + i) * 4 + kc) * 64 + lane)) * 8);
    const float* gi = gi0 + (size_t)(t * G_ + bid * 2 + g2) * 384;
    float gir = gi[f], giz = gi[128 + f], gin = gi[256 + f];

    floatx4 acc[6];
#pragma unroll
    for (int i = 0; i < 6; ++i) { floatx4 z = {0.f, 0.f, 0.f, 0.f}; acc[i] = z; }
#pragma unroll
    for (int kc = 0; kc < 4; ++kc) {
      f16x8 a = *(const f16x8*)(hb0 + mm * 136 + kc * 32 + quad * 8);
#pragma unroll
      for (int i = 0; i < 6; ++i)
        acc[i] = __builtin_amdgcn_mfma_f32_16x16x32_f16(a, B0[i * 4 + kc], acc[i], 0, 0, 0);
    }
    if (quad == 0) {
#pragma unroll
      for (int i = 0; i < 6; ++i) {
        ghb[0 * 384 + wave * 96 + i * 16 + mm] = acc[i][0];
        ghb[1 * 384 + wave * 96 + i * 16 + mm] = acc[i][1];
      }
    }
    __syncthreads();

    {
      float hr = ghb[g2 * 384 + f];
      float hz = ghb[g2 * 384 + 128 + f];
      float hn = ghb[g2 * 384 + 256 + f];
      float r = sig_fast(gir + hr + br0);
      float z = sig_fast(giz + hz + bz0);
      float nn = tanh_fast(gin + bni0 + r * (hn + bnh0));
      h0 = (1.0f - z) * nn + z * h0;
      hb0[g2 * 136 + f] = (f16)h0;
    }
    __syncthreads();

    floatx4 accx[6], acch[6];
#pragma unroll
    for (int i = 0; i < 6; ++i) {
      floatx4 z = {0.f, 0.f, 0.f, 0.f}; accx[i] = z; acch[i] = z;
    }
#pragma unroll
    for (int kc = 0; kc < 4; ++kc) {
      f16x8 ax = *(const f16x8*)(hb0 + mm * 136 + kc * 32 + quad * 8);
      f16x8 ah = *(const f16x8*)(hb1 + mm * 136 + kc * 32 + quad * 8);
#pragma unroll
      for (int i = 0; i < 6; ++i) {
        accx[i] = __builtin_amdgcn_mfma_f32_16x16x32_f16(ax, Bs[i * 4 + kc], accx[i], 0, 0, 0);
        acch[i] = __builtin_amdgcn_mfma_f32_16x16x32_f16(ah, B1[i * 4 + kc], acch[i], 0, 0, 0);
      }
    }
    if (quad == 0) {
#pragma unroll
      for (int i = 0; i < 6; ++i) {
        gib[0 * 384 + wave * 96 + i * 16 + mm] = accx[i][0];
        gib[1 * 384 + wave * 96 + i * 16 + mm] = accx[i][1];
        ghb[0 * 384 + wave * 96 + i * 16 + mm] = acch[i][0];
        ghb[1 * 384 + wave * 96 + i * 16 + mm] = acch[i][1];
      }
    }
    __syncthreads();

    {
      float i1r = gib[g2 * 384 + f];
      float i1z = gib[g2 * 384 + 128 + f];
      float i1n = gib[g2 * 384 + 256 + f];
      float hr = ghb[g2 * 384 + f];
      float hz = ghb[g2 * 384 + 128 + f];
      float hn = ghb[g2 * 384 + 256 + f];
      float r = sig_fast(i1r + hr + br1);
      float z = sig_fast(i1z + hz + bz1);
      float nn = tanh_fast(i1n + bni1 + r * (hn + bnh1));
      h1 = (1.0f - z) * nn + z * h1;
      hb1[g2 * 136 + f] = (f16)h1;
    }
    __syncthreads();
  }

  h1s[g2 * 128 + f] = h1;
  __syncthreads();
  if (tid < 2 * C_) {
    int gg = tid / C_, c = tid - gg * C_;
    float s = bc[c];
    const float* wr = Wc + (size_t)c * 128;
    const float* hr = h1s + gg * 128;
    for (int k = 0; k < 128; k += 4) {
      float4 w = *(const float4*)(wr + k);
      s += hr[k] * w.x + hr[k + 1] * w.y + hr[k + 2] * w.z + hr[k + 3] * w.w;
    }
    out[(bid * 2 + gg) * C_ + c] = s;
  }
}

extern "C" void kernel_launch(void* const* d_in, const int* in_sizes, int n_in,
                              void* d_out, int out_size, void* d_ws, size_t ws_size,
                              hipStream_t stream) {
  const float* x    = (const float*)d_in[0];
  const int*   ei   = (const int*)d_in[1];
  const int*   batch= (const int*)d_in[2];
  const float* W1   = (const float*)d_in[3];
  const float* b1   = (const float*)d_in[4];
  const float* W2   = (const float*)d_in[5];
  const float* b2   = (const float*)d_in[6];
  const float* Wih0 = (const float*)d_in[7];
  const float* Whh0 = (const float*)d_in[8];
  const float* bih0 = (const float*)d_in[9];
  const float* bhh0 = (const float*)d_in[10];
  const float* Wih1 = (const float*)d_in[11];
  const float* Whh1 = (const float*)d_in[12];
  const float* bih1 = (const float*)d_in[13];
  const float* bhh1 = (const float*)d_in[14];
  const float* Wc   = (const float*)d_in[15];
  const float* bc   = (const float*)d_in[16];
  float* out = (float*)d_out;

  char* ws = (char*)d_ws;
  f16*   Xh    = (f16*)(ws + OFF_XH);
  f16*   A1    = (f16*)(ws + OFF_A1);
  f16*   H1    = (f16*)(ws + OFF_H1);
  f16*   A2    = A1;                 // A1 dead after GEMM1
  f16*   H2    = Xh;                 // Xh dead after AGG1
  int2*  rec   = (int2*)(ws + OFF_REC);
  int*   degI  = (int*)(ws + OFF_DEG);
  int*   fillc = (int*)(ws + OFF_FILL);
  int*   cntG  = (int*)(ws + OFF_CNTG);
  int*   fillb = (int*)(ws + OFF_FILLB);
  float* dinv  = (float*)(ws + OFF_DINV);
  int*   rp    = (int*)(ws + OFF_RP);
  f16*   Wp    = (f16*)(ws + OFF_WP);
  int*   brp   = (int*)(ws + OFF_BRP);
  int*   blist = (int*)(ws + OFF_BLIST);
  f16*   embh  = (f16*)(ws + OFF_EMBH);
  f16*   gp    = (f16*)(ws + OFF_GPACK);
  float* gi0   = (float*)(ws + OFF_GI0);

  hipMemsetAsync(ws + OFF_DEG, 0, ZERO_BYTES, stream);

  cvt_kernel<<<10000, 256, 0, stream>>>(x, Xh);
  packall_kernel<<<896, 256, 0, stream>>>(W1, W2, Wp, Wih0, Whh0, Wih1, Whh1, gp);
  deg_kernel<<<5000, 256, 0, stream>>>(ei, degI);
  node_kernel<<<313, 256, 0, stream>>>(degI, dinv, batch, cntG);
  scan_kernel<<<9, 1024, 0, stream>>>(degI, rp, cntG, brp);
  fill_kernel<<<5000, 256, 0, stream>>>(ei, rp, fillc, dinv, rec, batch, brp, fillb, blist);

  agg_kernel<<<20000, 256, 0, stream>>>(Xh, A1, rp, rec, dinv);
  gemm_kernel<<<1250, 256, 0, stream>>>(A1, Wp, b1, H1);
  agg_kernel<<<20000, 256, 0, stream>>>(H1, A2, rp, rec, dinv);
  gemm_kernel<<<1250, 256, 0, stream>>>(A2, Wp + 16384, b2, H2);

  pool_kernel<<<64, 256, 0, stream>>>(H2, brp, blist, embh);
  gi0_kernel<<<4, 256, 0, stream>>>(embh, gp, gi0);
  gru_fused<<<16, 256, 0, stream>>>(gp, gi0, bih0, bhh0, bih1, bhh1, Wc, bc, out);
}

// Round 7
// 426.516 us; speedup vs baseline: 1.8519x; 1.1445x over previous
//
#include <hip/hip_runtime.h>

#define T_ 8
#define N_ 10000
#define E_ 160000
#define G_ 32
#define C_ 10
#define F_ 128

typedef _Float16 f16;
typedef _Float16 f16x2 __attribute__((ext_vector_type(2)));
typedef _Float16 f16x4 __attribute__((ext_vector_type(4)));
typedef _Float16 f16x8 __attribute__((ext_vector_type(8)));
typedef float floatx4 __attribute__((ext_vector_type(4)));

static constexpr size_t ROWS = (size_t)T_ * N_;   // 80000

// ---------------- workspace layout (bytes) ----------------
// Atomic counters are padded to one counter per 64B line (stride-16 ints):
// line-granular serialization at the coherence point was fill's bottleneck (R6).
static constexpr size_t OFF_XH    = 0;          // f16 [80000][128] X' = dinv*X (reused as H2)
static constexpr size_t OFF_A1    = 20480000;   // f16 [80000][128] (reused as A2)
static constexpr size_t OFF_H1    = 40960000;   // f16 [80000][128] H1' = dinv*H1
static constexpr size_t OFF_REC   = 61440000;   // int [T][E] src only (coef eliminated)
static constexpr size_t OFF_DEG   = 66560000;   // int [T][N] stride16 -- zeroed
static constexpr size_t OFF_FILLC = 71680000;   // int [T][N] stride16 -- zeroed
static constexpr size_t OFF_CNTG  = 76800000;   // int [T*G] stride16  -- zeroed
static constexpr size_t OFF_FILLB = 76816384;   // int [T*G] stride16  -- zeroed
static constexpr size_t ZERO_BYTES = 10272768;  // DEG..FILLB contiguous
static constexpr size_t OFF_DINV  = 76832768;   // float [T][N]
static constexpr size_t OFF_RP    = 77152768;   // int [T][N+1]
static constexpr size_t OFF_WP    = 77472800;   // f16 packed W1,W2 (2*16384)
static constexpr size_t OFF_BRP   = 77538336;   // int [T*G+1]
static constexpr size_t OFF_BLIST = 77539392;   // int [80000]
static constexpr size_t OFF_EMBH  = 77859392;   // f16 [256][128]
static constexpr size_t OFF_GPACK = 77924928;   // f16 4*49152 packed GRU weights
static constexpr size_t OFF_GI0   = 78318144;   // float [256][384]
// end ~78.7 MB

// ---------------- fast gates (v_exp_f32 / v_rcp_f32, ~1 ulp) ----------------
__device__ __forceinline__ float sig_fast(float x) {
  return __builtin_amdgcn_rcpf(1.0f + __builtin_amdgcn_exp2f(-1.4426950408889634f * x));
}
__device__ __forceinline__ float tanh_fast(float x) {
  return 1.0f - 2.0f * __builtin_amdgcn_rcpf(1.0f + __builtin_amdgcn_exp2f(2.8853900817779268f * x));
}

// ---------------- degree histogram (by dst), line-padded counters ----------------
__global__ void deg_kernel(const int* __restrict__ ei, int* __restrict__ degI) {
  int gid = blockIdx.x * 256 + threadIdx.x;     // exactly T*E
  int t = gid / E_, e = gid - t * E_;
  int dst = ei[(size_t)t * 2 * E_ + E_ + e];
  atomicAdd(&degI[(t * N_ + dst) * 16], 1);
}

// ---------------- per-node: dinv + group counts (padded) ----------------
__global__ void node_kernel(const int* __restrict__ degI, float* __restrict__ dinv,
                            const int* __restrict__ batch, int* __restrict__ cntG) {
  int gid = blockIdx.x * 256 + threadIdx.x;
  if (gid < (int)ROWS) {
    dinv[gid] = rsqrtf((float)degI[gid * 16] + 1.0f);
    atomicAdd(&cntG[((gid / N_) * G_ + batch[gid]) * 16], 1);
  }
}

// ---------------- fp32 -> fp16 convert, pre-scaled: X' = dinv[row] * x ----------------
__global__ void cvt_kernel(const float* __restrict__ x, const float* __restrict__ dinv,
                           f16* __restrict__ xh) {
  size_t i = ((size_t)blockIdx.x * 256 + threadIdx.x) * 4;
  float4 v = *(const float4*)(x + i);
  float d = dinv[i >> 7];
  f16x4 o; o.x = (f16)(v.x * d); o.y = (f16)(v.y * d);
  o.z = (f16)(v.z * d); o.w = (f16)(v.w * d);
  *(f16x4*)(xh + i) = o;
}

// ---------------- per-t exclusive scan of deg -> row_ptr; block 8 = group scan ----------------
__global__ void scan_kernel(const int* __restrict__ degI, int* __restrict__ rp,
                            const int* __restrict__ cntG, int* __restrict__ brp) {
  __shared__ int wsum[16];
  __shared__ int carry;
  int t = blockIdx.x, tid = threadIdx.x, lane = tid & 63, wid = tid >> 6;
  if (t == 8) {                                  // tiny scan over T*G group counts
    int v = (tid < 256) ? cntG[tid * 16] : 0;
    for (int ofs = 1; ofs < 64; ofs <<= 1) {
      int u = __shfl_up(v, ofs);
      if (lane >= ofs) v += u;
    }
    if (lane == 63 && wid < 4) wsum[wid] = v;
    __syncthreads();
    if (tid < 256) {
      int base = 0;
      for (int w = 0; w < wid; ++w) base += wsum[w];
      if (tid == 0) brp[0] = 0;
      brp[tid + 1] = v + base;
    }
    return;
  }
  if (tid == 0) { carry = 0; rp[t * (N_ + 1)] = 0; }
  __syncthreads();
  const int* d = degI + (size_t)t * N_ * 16;
  int* r = rp + t * (N_ + 1);
  for (int c0 = 0; c0 < N_; c0 += 1024) {
    int i = c0 + tid;
    int v = (i < N_) ? d[i * 16] : 0;
    for (int ofs = 1; ofs < 64; ofs <<= 1) {
      int u = __shfl_up(v, ofs);
      if (lane >= ofs) v += u;
    }
    if (lane == 63) wsum[wid] = v;
    __syncthreads();
    if (wid == 0) {
      int w = (lane < 16) ? wsum[lane] : 0;
      for (int ofs = 1; ofs < 16; ofs <<= 1) {
        int u = __shfl_up(w, ofs);
        if (lane >= ofs) w += u;
      }
      if (lane < 16) wsum[lane] = w;
    }
    __syncthreads();
    int base = carry + (wid ? wsum[wid - 1] : 0);
    if (i < N_) r[i + 1] = v + base;
    __syncthreads();
    if (tid == 0) carry += wsum[15];
    __syncthreads();
  }
}

// ---------------- CSR fill (XCD-swizzled, 4B record, padded counters) + batch fill ----------------
__global__ void fill_kernel(const int* __restrict__ ei, const int* __restrict__ rp,
                            int* __restrict__ fillc, int* __restrict__ rec,
                            const int* __restrict__ batch, const int* __restrict__ brp,
                            int* __restrict__ fillb, int* __restrict__ blist) {
  int b = blockIdx.x;                           // 5000
  int t = b & 7, i = b >> 3;                    // 625 chunks per t
  int e = i * 256 + threadIdx.x;                // < E
  int src = ei[(size_t)t * 2 * E_ + e];
  int dst = ei[(size_t)t * 2 * E_ + E_ + e];
  int pos = rp[t * (N_ + 1) + dst] + atomicAdd(&fillc[(t * N_ + dst) * 16], 1);
  rec[(size_t)t * E_ + pos] = src;
  // folded batch-CSR fill (first 313 block-equivalents of work)
  int gid = b * 256 + threadIdx.x;
  if (gid < (int)ROWS) {
    int tt = gid / N_;
    int g = batch[gid];
    int p2 = brp[tt * G_ + g] + atomicAdd(&fillb[(tt * G_ + g) * 16], 1);
    blist[p2] = gid;
  }
}

// ---------------- aggregation: out = dinv[row] * (sum X'[src] + X'[row]) ----------------
__global__ void agg_kernel(const f16* __restrict__ X, f16* __restrict__ A,
                           const int* __restrict__ rp, const int* __restrict__ rec,
                           const float* __restrict__ dinv) {
  int wave = threadIdx.x >> 6, lane = threadIdx.x & 63;
  int b = blockIdx.x;
  int t = b & 7, i = b >> 3;
  int n = i * 4 + wave;
  int row = t * N_ + n;
  float ds = dinv[row];
  f16x2 xv = *(const f16x2*)(X + (size_t)row * F_ + 2 * lane);
  float a00 = (float)xv.x, a01 = (float)xv.y;   // self term (X' already has one dinv)
  float a10 = 0.f, a11 = 0.f, a20 = 0.f, a21 = 0.f, a30 = 0.f, a31 = 0.f;
  int beg = rp[t * (N_ + 1) + n], end = rp[t * (N_ + 1) + n + 1];
  beg = __builtin_amdgcn_readfirstlane(beg);
  end = __builtin_amdgcn_readfirstlane(end);
  const int* rc = rec + (size_t)t * E_;
  const f16* Xt = X + (size_t)t * N_ * F_;
  int e = beg;
  for (; e + 3 < end; e += 4) {
    int s0 = rc[e], s1 = rc[e + 1], s2 = rc[e + 2], s3 = rc[e + 3];
    f16x2 h0 = *(const f16x2*)(Xt + (size_t)s0 * F_ + 2 * lane);
    f16x2 h1 = *(const f16x2*)(Xt + (size_t)s1 * F_ + 2 * lane);
    f16x2 h2 = *(const f16x2*)(Xt + (size_t)s2 * F_ + 2 * lane);
    f16x2 h3 = *(const f16x2*)(Xt + (size_t)s3 * F_ + 2 * lane);
    a00 += (float)h0.x; a01 += (float)h0.y;
    a10 += (float)h1.x; a11 += (float)h1.y;
    a20 += (float)h2.x; a21 += (float)h2.y;
    a30 += (float)h3.x; a31 += (float)h3.y;
  }
  for (; e < end; ++e) {
    int s = rc[e];
    f16x2 hv = *(const f16x2*)(Xt + (size_t)s * F_ + 2 * lane);
    a00 += (float)hv.x; a01 += (float)hv.y;
  }
  float r0 = ds * ((a00 + a10) + (a20 + a30));
  float r1 = ds * ((a01 + a11) + (a21 + a31));
  f16x2 o; o.x = (f16)r0; o.y = (f16)r1;
  *(f16x2*)(A + (size_t)row * F_ + 2 * lane) = o;
}

// ---------------- pack W1/W2 + GRU weights into MFMA B-frag layout (merged) ----------------
__global__ void packall_kernel(const float* __restrict__ W1, const float* __restrict__ W2,
                               f16* __restrict__ Wp,
                               const float* __restrict__ A0, const float* __restrict__ A1,
                               const float* __restrict__ A2, const float* __restrict__ A3,
                               f16* __restrict__ gp) {
  int idx = blockIdx.x * 256 + threadIdx.x;     // < 896*256 = 229376
  if (idx < 32768) {
    const float* W = (idx < 16384) ? W1 : W2;
    int l = idx & 16383;
    int j = l & 7, lane = (l >> 3) & 63, ct = (l >> 9) & 7, kc = (l >> 12) & 3;
    int k = kc * 32 + ((lane >> 4) & 3) * 8 + j;
    int n = ct * 16 + (lane & 15);
    Wp[idx] = (f16)W[k * 128 + n];
  } else {
    int gidx = idx - 32768;                     // < 196608
    int mat = gidx / 49152, l = gidx - mat * 49152;
    int j = l & 7, lane = (l >> 3) & 63, kc = (l >> 9) & 3, nt = l >> 11;
    int k = kc * 32 + ((lane >> 4) & 3) * 8 + j;
    int u = nt * 16 + (lane & 15);
    const float* W = (mat == 0) ? A0 : (mat == 1) ? A1 : (mat == 2) ? A2 : A3;
    gp[gidx] = (f16)W[u * 128 + k];
  }
}

// ---------------- GEMM: O = relu(A @ W + b) [* dinv-row scale], MFMA 16x16x32 ----------------
__global__ __launch_bounds__(256) void gemm_kernel(const f16* __restrict__ A,
                                                   const f16* __restrict__ Wp,
                                                   const float* __restrict__ bias,
                                                   const float* __restrict__ scale,
                                                   f16* __restrict__ O) {
  __shared__ f16x8 Bp[2048];                    // 32 KB packed W
  const f16x8* Wv = (const f16x8*)Wp;
  for (int i = threadIdx.x; i < 2048; i += 256) Bp[i] = Wv[i];
  __syncthreads();
  int wave = threadIdx.x >> 6, lane = threadIdx.x & 63;
  int quad = lane >> 4, m = lane & 15;
  int rowbase = blockIdx.x * 64 + wave * 16;
  const f16x8* Arow = (const f16x8*)(A + (size_t)(rowbase + m) * F_);
  floatx4 acc[8];
#pragma unroll
  for (int ct = 0; ct < 8; ++ct) { floatx4 z = {0.f, 0.f, 0.f, 0.f}; acc[ct] = z; }
#pragma unroll
  for (int kc = 0; kc < 4; ++kc) {
    f16x8 a = Arow[kc * 4 + quad];
#pragma unroll
    for (int ct = 0; ct < 8; ++ct)
      acc[ct] = __builtin_amdgcn_mfma_f32_16x16x32_f16(a, Bp[(kc * 8 + ct) * 64 + lane],
                                                       acc[ct], 0, 0, 0);
  }
  float sv[4];
#pragma unroll
  for (int r = 0; r < 4; ++r)
    sv[r] = scale ? scale[rowbase + quad * 4 + r] : 1.0f;
#pragma unroll
  for (int ct = 0; ct < 8; ++ct) {
    int colc = ct * 16 + m;
    float bv = bias[colc];
#pragma unroll
    for (int r = 0; r < 4; ++r) {
      int row = rowbase + quad * 4 + r;
      float v = fmaxf(acc[ct][r] + bv, 0.0f) * sv[r];
      O[(size_t)row * F_ + colc] = (f16)v;
    }
  }
}

// ---------------- pooling via batch-CSR gather -> f16 emb ----------------
__global__ void pool_kernel(const f16* __restrict__ H, const int* __restrict__ brp,
                            const int* __restrict__ blist, f16* __restrict__ embh) {
  int wave = threadIdx.x >> 6, lane = threadIdx.x & 63;
  int idx = blockIdx.x * 4 + wave;              // t*G+g, < 256
  int beg = brp[idx], end = brp[idx + 1];
  beg = __builtin_amdgcn_readfirstlane(beg);
  end = __builtin_amdgcn_readfirstlane(end);
  float a00 = 0.f, a01 = 0.f, a10 = 0.f, a11 = 0.f;
  float a20 = 0.f, a21 = 0.f, a30 = 0.f, a31 = 0.f;
  int e = beg;
  for (; e + 3 < end; e += 4) {
    int r0 = blist[e], r1 = blist[e + 1], r2 = blist[e + 2], r3 = blist[e + 3];
    f16x2 v0 = *(const f16x2*)(H + (size_t)r0 * F_ + 2 * lane);
    f16x2 v1 = *(const f16x2*)(H + (size_t)r1 * F_ + 2 * lane);
    f16x2 v2 = *(const f16x2*)(H + (size_t)r2 * F_ + 2 * lane);
    f16x2 v3 = *(const f16x2*)(H + (size_t)r3 * F_ + 2 * lane);
    a00 += (float)v0.x; a01 += (float)v0.y;
    a10 += (float)v1.x; a11 += (float)v1.y;
    a20 += (float)v2.x; a21 += (float)v2.y;
    a30 += (float)v3.x; a31 += (float)v3.y;
  }
  for (; e < end; ++e) {
    int r = blist[e];
    f16x2 v = *(const f16x2*)(H + (size_t)r * F_ + 2 * lane);
    a00 += (float)v.x; a01 += (float)v.y;
  }
  float d = 1.0f / fmaxf((float)(end - beg), 1.0f);
  f16x2 o;
  o.x = (f16)(((a00 + a10) + (a20 + a30)) * d);
  o.y = (f16)(((a01 + a11) + (a21 + a31)) * d);
  *(f16x2*)(embh + (size_t)idx * F_ + 2 * lane) = o;
}

// ---------------- gi0 = emb @ Wih0^T : M=256, K=128, N=384 ----------------
__global__ __launch_bounds__(256) void gi0_kernel(const f16* __restrict__ embh,
                                                  const f16* __restrict__ gp,
                                                  float* __restrict__ gi0) {
  int wave = threadIdx.x >> 6, lane = threadIdx.x & 63;
  int quad = lane >> 4, mm = lane & 15;
  int rowbase = blockIdx.x * 64 + wave * 16;    // grid 4
  const f16* Arow = embh + (size_t)(rowbase + mm) * 128;
  floatx4 acc[24];
#pragma unroll
  for (int nt = 0; nt < 24; ++nt) { floatx4 z = {0.f, 0.f, 0.f, 0.f}; acc[nt] = z; }
#pragma unroll
  for (int kc = 0; kc < 4; ++kc) {
    f16x8 a = *(const f16x8*)(Arow + kc * 32 + quad * 8);
#pragma unroll
    for (int nt = 0; nt < 24; ++nt) {
      f16x8 b = *(const f16x8*)(gp + (size_t)(((nt * 4 + kc) * 64 + lane)) * 8);
      acc[nt] = __builtin_amdgcn_mfma_f32_16x16x32_f16(a, b, acc[nt], 0, 0, 0);
    }
  }
#pragma unroll
  for (int nt = 0; nt < 24; ++nt)
#pragma unroll
    for (int r = 0; r < 4; ++r)
      gi0[(size_t)(rowbase + quad * 4 + r) * 384 + nt * 16 + mm] = acc[nt][r];
}

// ---------------- fused 2-layer GRU + final linear: 16 blocks x 2 groups ----------------
__global__ __launch_bounds__(256, 1) void gru_fused(
    const f16* __restrict__ gp, const float* __restrict__ gi0,
    const float* __restrict__ bih0, const float* __restrict__ bhh0,
    const float* __restrict__ bih1, const float* __restrict__ bhh1,
    const float* __restrict__ Wc, const float* __restrict__ bc,
    float* __restrict__ out) {
  __shared__ f16 hb0[16 * 136];
  __shared__ f16 hb1[16 * 136];
  __shared__ float ghb[2 * 384];
  __shared__ float gib[2 * 384];
  __shared__ float h1s[2 * 128];
  int tid = threadIdx.x, wave = tid >> 6, lane = tid & 63;
  int quad = lane >> 4, mm = lane & 15;
  int g2 = tid >> 7, f = tid & 127;
  int bid = blockIdx.x;

  f16x8 B0[24], B1[24];
#pragma unroll
  for (int i = 0; i < 6; ++i)
#pragma unroll
    for (int kc = 0; kc < 4; ++kc) {
      size_t off = (size_t)((((wave * 6 + i) * 4 + kc) * 64 + lane)) * 8;
      B0[i * 4 + kc] = *(const f16x8*)(gp + 1 * 49152 + off);
      B1[i * 4 + kc] = *(const f16x8*)(gp + 3 * 49152 + off);
    }
  float br0 = bih0[f] + bhh0[f];
  float bz0 = bih0[128 + f] + bhh0[128 + f];
  float bni0 = bih0[256 + f], bnh0 = bhh0[256 + f];
  float br1 = bih1[f] + bhh1[f];
  float bz1 = bih1[128 + f] + bhh1[128 + f];
  float bni1 = bih1[256 + f], bnh1 = bhh1[256 + f];

  for (int i = tid; i < 16 * 136; i += 256) { hb0[i] = (f16)0.f; hb1[i] = (f16)0.f; }
  float h0 = 0.f, h1 = 0.f;
  __syncthreads();

  const f16* wih1 = gp + 2 * 49152;
  for (int t = 0; t < T_; ++t) {
    f16x8 Bs[24];
#pragma unroll
    for (int i = 0; i < 6; ++i)
#pragma unroll
      for (int kc = 0; kc < 4; ++kc)
        Bs[i * 4 + kc] = *(const f16x8*)(wih1 +
            (size_t)((((wave * 6 + i) * 4 + kc) * 64 + lane)) * 8);
    const float* gi = gi0 + (size_t)(t * G_ + bid * 2 + g2) * 384;
    float gir = gi[f], giz = gi[128 + f], gin = gi[256 + f];

    floatx4 acc[6];
#pragma unroll
    for (int i = 0; i < 6; ++i) { floatx4 z = {0.f, 0.f, 0.f, 0.f}; acc[i] = z; }
#pragma unroll
    for (int kc = 0; kc < 4; ++kc) {
      f16x8 a = *(const f16x8*)(hb0 + mm * 136 + kc * 32 + quad * 8);
#pragma unroll
      for (int i = 0; i < 6; ++i)
        acc[i] = __builtin_amdgcn_mfma_f32_16x16x32_f16(a, B0[i * 4 + kc], acc[i], 0, 0, 0);
    }
    if (quad == 0) {
#pragma unroll
      for (int i = 0; i < 6; ++i) {
        ghb[0 * 384 + wave * 96 + i * 16 + mm] = acc[i][0];
        ghb[1 * 384 + wave * 96 + i * 16 + mm] = acc[i][1];
      }
    }
    __syncthreads();

    {
      float hr = ghb[g2 * 384 + f];
      float hz = ghb[g2 * 384 + 128 + f];
      float hn = ghb[g2 * 384 + 256 + f];
      float r = sig_fast(gir + hr + br0);
      float z = sig_fast(giz + hz + bz0);
      float nn = tanh_fast(gin + bni0 + r * (hn + bnh0));
      h0 = (1.0f - z) * nn + z * h0;
      hb0[g2 * 136 + f] = (f16)h0;
    }
    __syncthreads();

    floatx4 accx[6], acch[6];
#pragma unroll
    for (int i = 0; i < 6; ++i) {
      floatx4 z = {0.f, 0.f, 0.f, 0.f}; accx[i] = z; acch[i] = z;
    }
#pragma unroll
    for (int kc = 0; kc < 4; ++kc) {
      f16x8 ax = *(const f16x8*)(hb0 + mm * 136 + kc * 32 + quad * 8);
      f16x8 ah = *(const f16x8*)(hb1 + mm * 136 + kc * 32 + quad * 8);
#pragma unroll
      for (int i = 0; i < 6; ++i) {
        accx[i] = __builtin_amdgcn_mfma_f32_16x16x32_f16(ax, Bs[i * 4 + kc], accx[i], 0, 0, 0);
        acch[i] = __builtin_amdgcn_mfma_f32_16x16x32_f16(ah, B1[i * 4 + kc], acch[i], 0, 0, 0);
      }
    }
    if (quad == 0) {
#pragma unroll
      for (int i = 0; i < 6; ++i) {
        gib[0 * 384 + wave * 96 + i * 16 + mm] = accx[i][0];
        gib[1 * 384 + wave * 96 + i * 16 + mm] = accx[i][1];
        ghb[0 * 384 + wave * 96 + i * 16 + mm] = acch[i][0];
        ghb[1 * 384 + wave * 96 + i * 16 + mm] = acch[i][1];
      }
    }
    __syncthreads();

    {
      float i1r = gib[g2 * 384 + f];
      float i1z = gib[g2 * 384 + 128 + f];
      float i1n = gib[g2 * 384 + 256 + f];
      float hr = ghb[g2 * 384 + f];
      float hz = ghb[g2 * 384 + 128 + f];
      float hn = ghb[g2 * 384 + 256 + f];
      float r = sig_fast(i1r + hr + br1);
      float z = sig_fast(i1z + hz + bz1);
      float nn = tanh_fast(i1n + bni1 + r * (hn + bnh1));
      h1 = (1.0f - z) * nn + z * h1;
      hb1[g2 * 136 + f] = (f16)h1;
    }
    __syncthreads();
  }

  h1s[g2 * 128 + f] = h1;
  __syncthreads();
  if (tid < 2 * C_) {
    int gg = tid / C_, c = tid - gg * C_;
    float s = bc[c];
    const float* wr = Wc + (size_t)c * 128;
    const float* hr = h1s + gg * 128;
    for (int k = 0; k < 128; k += 4) {
      float4 w = *(const float4*)(wr + k);
      s += hr[k] * w.x + hr[k + 1] * w.y + hr[k + 2] * w.z + hr[k + 3] * w.w;
    }
    out[(bid * 2 + gg) * C_ + c] = s;
  }
}

extern "C" void kernel_launch(void* const* d_in, const int* in_sizes, int n_in,
                              void* d_out, int out_size, void* d_ws, size_t ws_size,
                              hipStream_t stream) {
  const float* x    = (const float*)d_in[0];
  const int*   ei   = (const int*)d_in[1];
  const int*   batch= (const int*)d_in[2];
  const float* W1   = (const float*)d_in[3];
  const float* b1   = (const float*)d_in[4];
  const float* W2   = (const float*)d_in[5];
  const float* b2   = (const float*)d_in[6];
  const float* Wih0 = (const float*)d_in[7];
  const float* Whh0 = (const float*)d_in[8];
  const float* bih0 = (const float*)d_in[9];
  const float* bhh0 = (const float*)d_in[10];
  const float* Wih1 = (const float*)d_in[11];
  const float* Whh1 = (const float*)d_in[12];
  const float* bih1 = (const float*)d_in[13];
  const float* bhh1 = (const float*)d_in[14];
  const float* Wc   = (const float*)d_in[15];
  const float* bc   = (const float*)d_in[16];
  float* out = (float*)d_out;

  char* ws = (char*)d_ws;
  f16*   Xh    = (f16*)(ws + OFF_XH);
  f16*   A1    = (f16*)(ws + OFF_A1);
  f16*   H1    = (f16*)(ws + OFF_H1);
  f16*   A2    = A1;                 // A1 dead after GEMM1
  f16*   H2    = Xh;                 // Xh dead after AGG1
  int*   rec   = (int*)(ws + OFF_REC);
  int*   degI  = (int*)(ws + OFF_DEG);
  int*   fillc = (int*)(ws + OFF_FILLC);
  int*   cntG  = (int*)(ws + OFF_CNTG);
  int*   fillb = (int*)(ws + OFF_FILLB);
  float* dinv  = (float*)(ws + OFF_DINV);
  int*   rp    = (int*)(ws + OFF_RP);
  f16*   Wp    = (f16*)(ws + OFF_WP);
  int*   brp   = (int*)(ws + OFF_BRP);
  int*   blist = (int*)(ws + OFF_BLIST);
  f16*   embh  = (f16*)(ws + OFF_EMBH);
  f16*   gp    = (f16*)(ws + OFF_GPACK);
  float* gi0   = (float*)(ws + OFF_GI0);

  hipMemsetAsync(ws + OFF_DEG, 0, ZERO_BYTES, stream);

  packall_kernel<<<896, 256, 0, stream>>>(W1, W2, Wp, Wih0, Whh0, Wih1, Whh1, gp);
  deg_kernel<<<5000, 256, 0, stream>>>(ei, degI);
  node_kernel<<<313, 256, 0, stream>>>(degI, dinv, batch, cntG);
  cvt_kernel<<<10000, 256, 0, stream>>>(x, dinv, Xh);
  scan_kernel<<<9, 1024, 0, stream>>>(degI, rp, cntG, brp);
  fill_kernel<<<5000, 256, 0, stream>>>(ei, rp, fillc, rec, batch, brp, fillb, blist);

  agg_kernel<<<20000, 256, 0, stream>>>(Xh, A1, rp, rec, dinv);
  gemm_kernel<<<1250, 256, 0, stream>>>(A1, Wp, b1, dinv, H1);
  agg_kernel<<<20000, 256, 0, stream>>>(H1, A2, rp, rec, dinv);
  gemm_kernel<<<1250, 256, 0, stream>>>(A2, Wp + 16384, b2, (const float*)nullptr, H2);

  pool_kernel<<<64, 256, 0, stream>>>(H2, brp, blist, embh);
  gi0_kernel<<<4, 256, 0, stream>>>(embh, gp, gi0);
  gru_fused<<<16, 256, 0, stream>>>(gp, gi0, bih0, bhh0, bih1, bhh1, Wc, bc, out);
}